// Round 5
// baseline (707.704 us; speedup 1.0000x reference)
//
#include <hip/hip_runtime.h>
#include <math.h>

// Deformable-DETR encoder, 2 layers. bf16-MFMA GEMMs + 2-phase MSDA sampling.
// Round 5: barrier-free full-N gemm_ln kernel fusing residual+LayerNorm into
// the two N=256 GEMMs (outproj+LN1, FFN2+LN2). B-frags direct from L2.

#define S_TOT 13294
#define BATCH 2
#define M_TOT (BATCH * S_TOT)     // 26588
#define M_PAD 26624               // 208 * 128 = 416 * 64

typedef __attribute__((ext_vector_type(8))) short short8;
typedef __attribute__((ext_vector_type(4))) float floatx4;

#define AS1C(p) ((const __attribute__((address_space(1))) void*)(p))
#define AS3(p)  ((__attribute__((address_space(3))) void*)(p))

static __device__ __forceinline__ unsigned short f2bf(float x) {
    union { float f; unsigned u; } v; v.f = x;
    unsigned r = v.u + 0x7FFFu + ((v.u >> 16) & 1u);
    return (unsigned short)(r >> 16);
}
static __device__ __forceinline__ float bflo(unsigned u) {
    union { unsigned u; float f; } v; v.u = u << 16; return v.f;
}
static __device__ __forceinline__ float bfhi(unsigned u) {
    union { unsigned u; float f; } v; v.u = u & 0xFFFF0000u; return v.f;
}

// ---------------------------------------------------------------------------
// bf16 MFMA GEMM (generic): C[M,N] = A[Mpad,K] @ BT[N,K] + bias, split bias,
// optional residual/relu, f32/bf16 out. 128x128 tile, m97 staging.
// ---------------------------------------------------------------------------
template<bool RELU, bool RES, bool F32OUT, bool BF16OUT>
__global__ __launch_bounds__(256)
void mgemm(const unsigned short* __restrict__ A,
           const unsigned short* __restrict__ BT,
           const float* __restrict__ bias,
           const float* __restrict__ bias2, int nsplit,
           const float* __restrict__ R,
           float* __restrict__ Cf,
           unsigned short* __restrict__ Cb,
           int M, int N, int K)
{
    __shared__ __align__(16) unsigned short smemA[128 * 32];
    __shared__ __align__(16) unsigned short smemB[128 * 32];
    const int tid  = threadIdx.x;
    const int lane = tid & 63;
    const int w    = tid >> 6;
    const int wm   = w & 1, wn = w >> 1;
    const int lr   = lane & 15, quad = lane >> 4;
    const int bm   = blockIdx.y * 128;
    const int bn   = blockIdx.x * 128;

    floatx4 acc[4][4];
    #pragma unroll
    for (int i = 0; i < 4; ++i)
        #pragma unroll
        for (int j = 0; j < 4; ++j)
            acc[i][j] = (floatx4){0.f, 0.f, 0.f, 0.f};

    const int srow = lane >> 2;
    const int selt = (lane & 3) << 3;

    for (int k0 = 0; k0 < K; k0 += 32) {
        #pragma unroll
        for (int jj = 0; jj < 2; ++jj) {
            const int j = 2 * w + jj;
            const unsigned short* ga = A  + (size_t)(bm + j * 16 + srow) * K + k0 + selt;
            const unsigned short* gb = BT + (size_t)(bn + j * 16 + srow) * K + k0 + selt;
            __builtin_amdgcn_global_load_lds(AS1C(ga), AS3(smemA + j * 512), 16, 0, 0);
            __builtin_amdgcn_global_load_lds(AS1C(gb), AS3(smemB + j * 512), 16, 0, 0);
        }
        __syncthreads();

        short8 av[4], bv[4];
        #pragma unroll
        for (int mi = 0; mi < 4; ++mi)
            av[mi] = *(const short8*)&smemA[(wm * 64 + mi * 16 + lr) * 32 + quad * 8];
        #pragma unroll
        for (int ni = 0; ni < 4; ++ni)
            bv[ni] = *(const short8*)&smemB[(wn * 64 + ni * 16 + lr) * 32 + quad * 8];
        #pragma unroll
        for (int mi = 0; mi < 4; ++mi)
            #pragma unroll
            for (int ni = 0; ni < 4; ++ni)
                acc[mi][ni] = __builtin_amdgcn_mfma_f32_16x16x32_bf16(
                    av[mi], bv[ni], acc[mi][ni], 0, 0, 0);
        __syncthreads();
    }

    #pragma unroll
    for (int mi = 0; mi < 4; ++mi) {
        #pragma unroll
        for (int ni = 0; ni < 4; ++ni) {
            #pragma unroll
            for (int r = 0; r < 4; ++r) {
                const int row = bm + wm * 64 + mi * 16 + quad * 4 + r;
                const int col = bn + wn * 64 + ni * 16 + lr;
                float bb = (col < nsplit) ? bias[col] : bias2[col - nsplit];
                float v = acc[mi][ni][r] + bb;
                if (RES) { if (row < M) v += R[(size_t)row * N + col]; }
                if (RELU) v = fmaxf(v, 0.0f);
                if (F32OUT) Cf[(size_t)row * N + col] = v;
                if (BF16OUT) Cb[(size_t)row * N + col] = f2bf(v);
            }
        }
    }
}

// ---------------------------------------------------------------------------
// Fused GEMM(N=256) + bias + residual + LayerNorm.  Barrier-free.
// Block = 256 thr = 4 waves; wave w owns rows [b*64+w*16, +16) x ALL 256 cols
// (16 accumulator tiles). A/B frags loaded directly from global (B L2-hot).
// Epilogue: per-row LN via width-16 shfl_xor butterflies (rows are in-wave).
// Writes outF f32 (post-LN) and optionally outB bf16.
// ---------------------------------------------------------------------------
template<int KDIV32, bool HASB>
__global__ __launch_bounds__(256)
void gemm_ln(const unsigned short* __restrict__ A,
             const unsigned short* __restrict__ BT,
             const float* __restrict__ bias,
             const float* __restrict__ R,
             const float* __restrict__ g,
             const float* __restrict__ beta,
             float* __restrict__ outF,
             unsigned short* __restrict__ outB, int M)
{
    const int K    = KDIV32 * 32;
    const int lane = threadIdx.x & 63;
    const int w    = threadIdx.x >> 6;
    const int lr   = lane & 15, quad = lane >> 4;
    const int row0 = blockIdx.x * 64 + w * 16;

    floatx4 acc[16];
    #pragma unroll
    for (int ni = 0; ni < 16; ++ni) acc[ni] = (floatx4){0.f, 0.f, 0.f, 0.f};

    const unsigned short* arow = A + (size_t)(row0 + lr) * K + quad * 8;
    const unsigned short* bp[16];
    #pragma unroll
    for (int ni = 0; ni < 16; ++ni)
        bp[ni] = BT + (size_t)(ni * 16 + lr) * K + quad * 8;

    #pragma unroll 2
    for (int kk = 0; kk < KDIV32; ++kk) {
        const short8 a = *(const short8*)(arow + kk * 32);
        #pragma unroll
        for (int ni = 0; ni < 16; ++ni) {
            const short8 b = *(const short8*)(bp[ni] + kk * 32);
            acc[ni] = __builtin_amdgcn_mfma_f32_16x16x32_bf16(a, b, acc[ni], 0, 0, 0);
        }
    }

    // epilogue: lane holds (row = row0 + quad*4 + reg, col = ni*16 + lr)
    float bs[16], gs[16], bt[16];
    #pragma unroll
    for (int ni = 0; ni < 16; ++ni) {
        bs[ni] = bias[ni * 16 + lr];
        gs[ni] = g[ni * 16 + lr];
        bt[ni] = beta[ni * 16 + lr];
    }
    #pragma unroll
    for (int reg = 0; reg < 4; ++reg) {
        const int grow = row0 + quad * 4 + reg;
        const bool act = grow < M;
        float v[16];
        float s = 0.f, s2 = 0.f;
        #pragma unroll
        for (int ni = 0; ni < 16; ++ni) {
            float rv = act ? R[(size_t)grow * 256 + ni * 16 + lr] : 0.f;
            float x = acc[ni][reg] + bs[ni] + rv;
            v[ni] = x; s += x; s2 += x * x;
        }
        #pragma unroll
        for (int o = 1; o < 16; o <<= 1) {
            s  += __shfl_xor(s,  o, 64);
            s2 += __shfl_xor(s2, o, 64);
        }
        const float mean = s * (1.0f / 256.0f);
        const float var  = s2 * (1.0f / 256.0f) - mean * mean;
        const float rs   = rsqrtf(var + 1e-5f);
        if (act) {
            #pragma unroll
            for (int ni = 0; ni < 16; ++ni) {
                const float y = (v[ni] - mean) * rs * gs[ni] + bt[ni];
                outF[(size_t)grow * 256 + ni * 16 + lr] = y;
                if (HASB) outB[(size_t)grow * 256 + ni * 16 + lr] = f2bf(y);
            }
        }
    }
}

// ---------------------------------------------------------------------------
// fp32 [M,256] -> bf16 [M_PAD,256] with zero padding rows (layer 0 only)
// ---------------------------------------------------------------------------
__global__ __launch_bounds__(256)
void convpad(const float* __restrict__ X, unsigned short* __restrict__ Y, int M)
{
    const int idx = blockIdx.x * 256 + threadIdx.x;
    const int row = idx >> 6;
    const int c4  = (idx & 63) << 2;
    if (row >= M_PAD) return;
    float4 v = {0.f, 0.f, 0.f, 0.f};
    if (row < M) v = ((const float4*)(X + (size_t)row * 256))[c4 >> 2];
    unsigned p0 = (unsigned)f2bf(v.x) | ((unsigned)f2bf(v.y) << 16);
    unsigned p1 = (unsigned)f2bf(v.z) | ((unsigned)f2bf(v.w) << 16);
    uint2 o; o.x = p0; o.y = p1;
    *(uint2*)(Y + (size_t)row * 256 + c4) = o;
}

// ---------------------------------------------------------------------------
// Weight transpose+convert: W[K,N] fp32 -> WT[N,K] bf16. 32x32 tiles.
// ---------------------------------------------------------------------------
__global__ __launch_bounds__(256)
void wtrans(const float* __restrict__ W, unsigned short* __restrict__ WT,
            int K, int N)
{
    __shared__ float t[32][33];
    const int n0 = blockIdx.x * 32, k0 = blockIdx.y * 32;
    const int c = threadIdx.x & 31, r0 = threadIdx.x >> 5;
    #pragma unroll
    for (int rr = r0; rr < 32; rr += 8)
        t[rr][c] = W[(size_t)(k0 + rr) * N + n0 + c];
    __syncthreads();
    #pragma unroll
    for (int rr = r0; rr < 32; rr += 8)
        WT[(size_t)(n0 + rr) * K + k0 + c] = f2bf(t[c][rr]);
}

// ---------------------------------------------------------------------------
// MSDA, 2-phase (unchanged from round 4).
// ---------------------------------------------------------------------------
__global__ __launch_bounds__(256)
void msda_kernel(const unsigned short* __restrict__ valb,
                 const float* __restrict__ oa,
                 const float* __restrict__ vr,
                 unsigned short* __restrict__ out)
{
    __shared__ __align__(16) char smeta[8 * 128 * 32];
    const int t = threadIdx.x;

    {
        const int wv = t >> 6, lane = t & 63;
        const int lqA = wv * 2 + (lane >> 5);
        const int bq = blockIdx.x * 8 + lqA;
        const int h = (lane >> 2) & 7;
        const int j = lane & 3;
        if (bq < M_TOT) {
            const int b = (bq >= S_TOT) ? 1 : 0;
            const int q = bq - b * S_TOT;
            int Hq, rr, cc;
            int lq;
            if (q < 10000)      { lq = 0; Hq = 100; rr = q / 100;              cc = q - rr * 100; }
            else if (q < 12500) { lq = 1; Hq = 50;  int r2 = q - 10000; rr = r2 / 50; cc = r2 - rr * 50; }
            else if (q < 13125) { lq = 2; Hq = 25;  int r2 = q - 12500; rr = r2 / 25; cc = r2 - rr * 25; }
            else                { lq = 3; Hq = 13;  int r2 = q - 13125; rr = r2 / 13; cc = r2 - rr * 13; }
            const float rxb = (cc + 0.5f) / (vr[(b * 4 + lq) * 2 + 0] * (float)Hq);
            const float ryb = (rr + 0.5f) / (vr[(b * 4 + lq) * 2 + 1] * (float)Hq);
            const int HWt[4] = {100, 50, 25, 13};
            const int stt[4] = {0, 10000, 12500, 13125};
            const int HW = HWt[j], st = stt[j];
            const float fW = (float)HW;
            const float refx = rxb * vr[(b * 4 + j) * 2 + 0];
            const float refy = ryb * vr[(b * 4 + j) * 2 + 1];
            const float* row = oa + (size_t)bq * 384;
            const float4 lg = *(const float4*)(row + 256 + h * 16 + j * 4);
            float mx = fmaxf(fmaxf(lg.x, lg.y), fmaxf(lg.z, lg.w));
            mx = fmaxf(mx, __shfl_xor(mx, 1, 64));
            mx = fmaxf(mx, __shfl_xor(mx, 2, 64));
            const float e0 = expf(lg.x - mx), e1 = expf(lg.y - mx);
            const float e2 = expf(lg.z - mx), e3 = expf(lg.w - mx);
            float ss = e0 + e1 + e2 + e3;
            ss += __shfl_xor(ss, 1, 64);
            ss += __shfl_xor(ss, 2, 64);
            const float inv = 1.0f / ss;
            const float4 oA = *(const float4*)(row + h * 32 + j * 8);
            const float4 oB = *(const float4*)(row + h * 32 + j * 8 + 4);
            const float oxs[4] = {oA.x, oA.z, oB.x, oB.z};
            const float oys[4] = {oA.y, oA.w, oB.y, oB.w};
            const float aw[4]  = {e0 * inv, e1 * inv, e2 * inv, e3 * inv};
            char* mb = smeta + (size_t)(lqA * 128 + h * 16 + j * 4) * 32;
            const int swz = ((h * 4 + j) & 7) << 4;
            #pragma unroll
            for (int p = 0; p < 4; ++p) {
                const float x = (refx + oxs[p] / fW) * fW - 0.5f;
                const float y = (refy + oys[p] / fW) * fW - 0.5f;
                const float x0f = floorf(x), y0f = floorf(y);
                const int x0 = (int)x0f, y0 = (int)y0f;
                const float fx = x - x0f, fy = y - y0f;
                const float wb[4] = {(1.f - fx) * (1.f - fy), fx * (1.f - fy),
                                     (1.f - fx) * fy,         fx * fy};
                const int xs[2] = {x0, x0 + 1};
                const int ys2[2] = {y0, y0 + 1};
                int iv[4]; float wv4[4];
                #pragma unroll
                for (int k = 0; k < 4; ++k) {
                    const int xi = xs[k & 1], yi = ys2[k >> 1];
                    const bool vld = ((unsigned)xi < (unsigned)HW) && ((unsigned)yi < (unsigned)HW);
                    const int xc = min(max(xi, 0), HW - 1);
                    const int yc = min(max(yi, 0), HW - 1);
                    iv[k] = ((st + yc * HW + xc) << 9) + (h << 6);
                    wv4[k] = vld ? wb[k] * aw[p] : 0.0f;
                }
                int4 i4; i4.x = iv[0]; i4.y = iv[1]; i4.z = iv[2]; i4.w = iv[3];
                float4 w4; w4.x = wv4[0]; w4.y = wv4[1]; w4.z = wv4[2]; w4.w = wv4[3];
                *(int4*)(mb + ((p * 32) ^ swz)) = i4;
                *(float4*)(mb + ((p * 32 + 16) ^ swz)) = w4;
            }
        }
    }
    __syncthreads();
    {
        const int lq2 = t >> 5;
        const int r = t & 31;
        const int h2 = r >> 2;
        const int cg = r & 3;
        const int bq2 = blockIdx.x * 8 + lq2;
        if (bq2 < M_TOT) {
            const int b2 = (bq2 >= S_TOT) ? 1 : 0;
            const char* vb = (const char*)valb + (size_t)b2 * ((size_t)S_TOT * 512) + cg * 16;
            float acc[8] = {0.f, 0.f, 0.f, 0.f, 0.f, 0.f, 0.f, 0.f};
            const char* mb2 = smeta + (size_t)(lq2 * 128 + h2 * 16) * 32;
            #pragma unroll 4
            for (int s = 0; s < 16; ++s) {
                const int swz2 = ((h2 * 4 + (s >> 2)) & 7) << 4;
                const int4  iv = *(const int4*)(mb2 + ((s * 32) ^ swz2));
                const float4 w4 = *(const float4*)(mb2 + ((s * 32 + 16) ^ swz2));
                const uint4 u0 = *(const uint4*)(vb + iv.x);
                const uint4 u1 = *(const uint4*)(vb + iv.y);
                const uint4 u2 = *(const uint4*)(vb + iv.z);
                const uint4 u3 = *(const uint4*)(vb + iv.w);
                #define ACC8(UU, WW) \
                    acc[0] = fmaf(WW, bflo(UU.x), acc[0]); acc[1] = fmaf(WW, bfhi(UU.x), acc[1]); \
                    acc[2] = fmaf(WW, bflo(UU.y), acc[2]); acc[3] = fmaf(WW, bfhi(UU.y), acc[3]); \
                    acc[4] = fmaf(WW, bflo(UU.z), acc[4]); acc[5] = fmaf(WW, bfhi(UU.z), acc[5]); \
                    acc[6] = fmaf(WW, bflo(UU.w), acc[6]); acc[7] = fmaf(WW, bfhi(UU.w), acc[7]);
                ACC8(u0, w4.x) ACC8(u1, w4.y) ACC8(u2, w4.z) ACC8(u3, w4.w)
                #undef ACC8
            }
            uint4 o;
            o.x = (unsigned)f2bf(acc[0]) | ((unsigned)f2bf(acc[1]) << 16);
            o.y = (unsigned)f2bf(acc[2]) | ((unsigned)f2bf(acc[3]) << 16);
            o.z = (unsigned)f2bf(acc[4]) | ((unsigned)f2bf(acc[5]) << 16);
            o.w = (unsigned)f2bf(acc[6]) | ((unsigned)f2bf(acc[7]) << 16);
            *(uint4*)(out + (size_t)bq2 * 256 + h2 * 32 + cg * 8) = o;
        }
    }
}

// ---------------------------------------------------------------------------
// Host-side orchestration
// ---------------------------------------------------------------------------
extern "C" void kernel_launch(void* const* d_in, const int* in_sizes, int n_in,
                              void* d_out, int out_size, void* d_ws, size_t ws_size,
                              hipStream_t stream)
{
    const float* src    = (const float*)d_in[0];
    const float* vr     = (const float*)d_in[2];
    const float* W_off  = (const float*)d_in[3];
    const float* b_off  = (const float*)d_in[4];
    const float* W_attn = (const float*)d_in[5];
    const float* b_attn = (const float*)d_in[6];
    const float* W_val  = (const float*)d_in[7];
    const float* b_val  = (const float*)d_in[8];
    const float* W_out  = (const float*)d_in[9];
    const float* b_out  = (const float*)d_in[10];
    const float* ln1_g  = (const float*)d_in[11];
    const float* ln1_b  = (const float*)d_in[12];
    const float* W1     = (const float*)d_in[13];
    const float* b1     = (const float*)d_in[14];
    const float* W2     = (const float*)d_in[15];
    const float* b2     = (const float*)d_in[16];
    const float* ln2_g  = (const float*)d_in[17];
    const float* ln2_b  = (const float*)d_in[18];
    float* out = (float*)d_out;

    const int M = M_TOT;

    // --- workspace (bytes), total 112,066,560 ---
    // [0,          40,894,464)  OA   f32 [M_PAD,384]    \ overlay: HBF bf16 [M_PAD,1024]
    // [40,894,464, 54,525,952)  VALB bf16 [M_PAD,256]   /
    // [54,525,952, 81,788,928)  T1   f32 [M_PAD,256]  (x1 = post-LN1)
    // [81,788,928, 95,420,416)  RB   bf16 [M_PAD,256]
    // [95,420,416,109,051,904)  YBF  bf16 [M_PAD,256]
    // [109,051,904,112,066,560) WT   bf16 transposed weights (both layers)
    char* wsb = (char*)d_ws;
    float*          OA   = (float*)wsb;
    unsigned short* VALB = (unsigned short*)(wsb + 40894464);
    unsigned short* HBF  = (unsigned short*)wsb;
    float*          T1   = (float*)(wsb + 54525952);
    unsigned short* RB   = (unsigned short*)(wsb + 81788928);
    unsigned short* YBF  = (unsigned short*)(wsb + 95420416);
    unsigned short* WT   = (unsigned short*)(wsb + 109051904);

    const size_t LWT = 753664;
    const size_t oOA = 0, oVal = 98304, oOut = 163840, oW1 = 229376, oW2 = 491520;

    for (int i = 0; i < 2; ++i) {
        unsigned short* wt = WT + i * LWT;
        wtrans<<<dim3(8, 8),  256, 0, stream>>>(W_off  + i * 65536,  wt + oOA,         256, 256);
        wtrans<<<dim3(4, 8),  256, 0, stream>>>(W_attn + i * 32768,  wt + oOA + 65536, 256, 128);
        wtrans<<<dim3(8, 8),  256, 0, stream>>>(W_val  + i * 65536,  wt + oVal,        256, 256);
        wtrans<<<dim3(8, 8),  256, 0, stream>>>(W_out  + i * 65536,  wt + oOut,        256, 256);
        wtrans<<<dim3(32, 8), 256, 0, stream>>>(W1     + i * 262144, wt + oW1,         256, 1024);
        wtrans<<<dim3(8, 32), 256, 0, stream>>>(W2     + i * 262144, wt + oW2,         1024, 256);
    }

    const int GM = M_PAD / 128;   // 208
    const int GL = M_PAD / 64;    // 416
    const dim3 blk(256);

    for (int i = 0; i < 2; ++i) {
        const float* xin = (i == 0) ? src : out;
        unsigned short* wt = WT + i * LWT;

        if (i == 0)
            convpad<<<dim3(M_PAD / 4), blk, 0, stream>>>(src, RB, M);

        // value projection (bf16 out) + fused off/attn projection (f32 out)
        mgemm<false,false,false,true><<<dim3(2, GM), blk, 0, stream>>>(
            RB, wt + oVal, b_val + i * 256, b_val + i * 256, 256,
            nullptr, nullptr, VALB, M, 256, 256);
        mgemm<false,false,true,false><<<dim3(3, GM), blk, 0, stream>>>(
            RB, wt + oOA, b_off + i * 256, b_attn + i * 128, 256,
            nullptr, OA, nullptr, M, 384, 256);

        // deformable sampling (2-phase), writes bf16
        msda_kernel<<<dim3((M + 7) / 8), blk, 0, stream>>>(VALB, OA, vr, YBF);

        // fused out-proj + residual(xin) + LN1 -> T1 (f32 post-LN) + RB (bf16)
        gemm_ln<8, true><<<dim3(GL), blk, 0, stream>>>(
            YBF, wt + oOut, b_out + i * 256, xin,
            ln1_g + i * 256, ln1_b + i * 256, T1, RB, M);

        // FFN1 (relu, bf16 hidden overlays OA+VALB)
        mgemm<true,false,false,true><<<dim3(8, GM), blk, 0, stream>>>(
            RB, wt + oW1, b1 + i * 1024, b1 + i * 1024, 1024,
            nullptr, nullptr, HBF, M, 1024, 256);

        // fused FFN2 + residual(T1) + LN2 -> out (f32) [+ RB bf16 on layer 0]
        if (i == 0)
            gemm_ln<32, true><<<dim3(GL), blk, 0, stream>>>(
                HBF, wt + oW2, b2 + i * 256, T1,
                ln2_g + i * 256, ln2_b + i * 256, out, RB, M);
        else
            gemm_ln<32, false><<<dim3(GL), blk, 0, stream>>>(
                HBF, wt + oW2, b2 + i * 256, T1,
                ln2_g + i * 256, ln2_b + i * 256, out, nullptr, M);
    }
}

// Round 6
// 516.255 us; speedup vs baseline: 1.3708x; 1.3708x over previous
//
#include <hip/hip_runtime.h>
#include <math.h>

// Deformable-DETR encoder, 2 layers. bf16-MFMA GEMMs + 2-phase MSDA sampling.
// Round 6: revert gemm_ln (latency-bound failure); add TM=64 mgemm tile for
// grid-starved N=256 GEMMs; merge val/off/attn projections into one N=640 GEMM.

#define S_TOT 13294
#define BATCH 2
#define M_TOT (BATCH * S_TOT)     // 26588
#define M_PAD 26624               // 208 * 128 = 416 * 64

typedef __attribute__((ext_vector_type(8))) short short8;
typedef __attribute__((ext_vector_type(4))) float floatx4;

#define AS1C(p) ((const __attribute__((address_space(1))) void*)(p))
#define AS3(p)  ((__attribute__((address_space(3))) void*)(p))

static __device__ __forceinline__ unsigned short f2bf(float x) {
    union { float f; unsigned u; } v; v.f = x;
    unsigned r = v.u + 0x7FFFu + ((v.u >> 16) & 1u);
    return (unsigned short)(r >> 16);
}
static __device__ __forceinline__ float bflo(unsigned u) {
    union { unsigned u; float f; } v; v.u = u << 16; return v.f;
}
static __device__ __forceinline__ float bfhi(unsigned u) {
    union { unsigned u; float f; } v; v.u = u & 0xFFFF0000u; return v.f;
}

// ---------------------------------------------------------------------------
// bf16 MFMA GEMM. TM=128: 128x128 tile, 4 waves 2x2 of 64x64 (m97 structure).
// TM=64: 64x128 tile, 4 waves of 64x32 — 2x the blocks for grid-starved GEMMs.
// PROJ epilogue routes cols: <256 -> bf16 Cb[.,256] (value), >=256 -> f32
// Cf[.,384] (off/attn), with 3-way bias select (block-uniform, no divergence).
// ---------------------------------------------------------------------------
template<int TM, bool RELU, bool RES, bool F32OUT, bool BF16OUT, bool PROJ>
__global__ __launch_bounds__(256)
void mgemm(const unsigned short* __restrict__ A,
           const unsigned short* __restrict__ BT,
           const float* __restrict__ bias,
           const float* __restrict__ bias2,
           const float* __restrict__ bias3,
           const float* __restrict__ R,
           float* __restrict__ Cf,
           unsigned short* __restrict__ Cb,
           int M, int N, int K)
{
    constexpr int WM = (TM == 128) ? 2 : 1;
    constexpr int WN = 4 / WM;
    constexpr int MI = TM / (WM * 16);    // 4
    constexpr int NI = 128 / (WN * 16);   // 4 (TM=128) or 2 (TM=64)
    __shared__ __align__(16) unsigned short smemA[TM * 32];
    __shared__ __align__(16) unsigned short smemB[128 * 32];
    const int tid  = threadIdx.x;
    const int lane = tid & 63;
    const int w    = tid >> 6;
    const int wm   = w % WM, wn = w / WM;
    const int lr   = lane & 15, quad = lane >> 4;
    const int bm   = blockIdx.y * TM;
    const int bn   = blockIdx.x * 128;

    floatx4 acc[MI][NI];
    #pragma unroll
    for (int i = 0; i < MI; ++i)
        #pragma unroll
        for (int j = 0; j < NI; ++j)
            acc[i][j] = (floatx4){0.f, 0.f, 0.f, 0.f};

    const int srow = lane >> 2;
    const int selt = (lane & 3) << 3;

    for (int k0 = 0; k0 < K; k0 += 32) {
        if (TM == 128) {
            #pragma unroll
            for (int jj = 0; jj < 2; ++jj) {
                const int j = 2 * w + jj;
                const unsigned short* ga = A  + (size_t)(bm + j * 16 + srow) * K + k0 + selt;
                const unsigned short* gb = BT + (size_t)(bn + j * 16 + srow) * K + k0 + selt;
                __builtin_amdgcn_global_load_lds(AS1C(ga), AS3(smemA + j * 512), 16, 0, 0);
                __builtin_amdgcn_global_load_lds(AS1C(gb), AS3(smemB + j * 512), 16, 0, 0);
            }
        } else {
            const unsigned short* ga = A + (size_t)(bm + w * 16 + srow) * K + k0 + selt;
            __builtin_amdgcn_global_load_lds(AS1C(ga), AS3(smemA + w * 512), 16, 0, 0);
            #pragma unroll
            for (int jj = 0; jj < 2; ++jj) {
                const int j = 2 * w + jj;
                const unsigned short* gb = BT + (size_t)(bn + j * 16 + srow) * K + k0 + selt;
                __builtin_amdgcn_global_load_lds(AS1C(gb), AS3(smemB + j * 512), 16, 0, 0);
            }
        }
        __syncthreads();

        short8 av[MI], bv[NI];
        #pragma unroll
        for (int mi = 0; mi < MI; ++mi)
            av[mi] = *(const short8*)&smemA[(wm * MI * 16 + mi * 16 + lr) * 32 + quad * 8];
        #pragma unroll
        for (int ni = 0; ni < NI; ++ni)
            bv[ni] = *(const short8*)&smemB[(wn * NI * 16 + ni * 16 + lr) * 32 + quad * 8];
        #pragma unroll
        for (int mi = 0; mi < MI; ++mi)
            #pragma unroll
            for (int ni = 0; ni < NI; ++ni)
                acc[mi][ni] = __builtin_amdgcn_mfma_f32_16x16x32_bf16(
                    av[mi], bv[ni], acc[mi][ni], 0, 0, 0);
        __syncthreads();
    }

    #pragma unroll
    for (int mi = 0; mi < MI; ++mi) {
        #pragma unroll
        for (int ni = 0; ni < NI; ++ni) {
            #pragma unroll
            for (int r = 0; r < 4; ++r) {
                const int row = bm + wm * MI * 16 + mi * 16 + quad * 4 + r;
                const int col = bn + wn * NI * 16 + ni * 16 + lr;
                if (PROJ) {
                    const float bb = (col < 256) ? bias[col]
                                   : (col < 512) ? bias2[col - 256]
                                                 : bias3[col - 512];
                    const float v = acc[mi][ni][r] + bb;
                    if (col < 256) Cb[(size_t)row * 256 + col] = f2bf(v);
                    else           Cf[(size_t)row * 384 + (col - 256)] = v;
                } else {
                    float v = acc[mi][ni][r] + bias[col];
                    if (RES) { if (row < M) v += R[(size_t)row * N + col]; }
                    if (RELU) v = fmaxf(v, 0.0f);
                    if (F32OUT) Cf[(size_t)row * N + col] = v;
                    if (BF16OUT) Cb[(size_t)row * N + col] = f2bf(v);
                }
            }
        }
    }
}

// ---------------------------------------------------------------------------
// fp32 [M,256] -> bf16 [M_PAD,256] with zero padding rows (layer 0 only)
// ---------------------------------------------------------------------------
__global__ __launch_bounds__(256)
void convpad(const float* __restrict__ X, unsigned short* __restrict__ Y, int M)
{
    const int idx = blockIdx.x * 256 + threadIdx.x;
    const int row = idx >> 6;
    const int c4  = (idx & 63) << 2;
    if (row >= M_PAD) return;
    float4 v = {0.f, 0.f, 0.f, 0.f};
    if (row < M) v = ((const float4*)(X + (size_t)row * 256))[c4 >> 2];
    unsigned p0 = (unsigned)f2bf(v.x) | ((unsigned)f2bf(v.y) << 16);
    unsigned p1 = (unsigned)f2bf(v.z) | ((unsigned)f2bf(v.w) << 16);
    uint2 o; o.x = p0; o.y = p1;
    *(uint2*)(Y + (size_t)row * 256 + c4) = o;
}

// ---------------------------------------------------------------------------
// Weight transpose+convert: W[K,N] fp32 -> WT[N,K] bf16. 32x32 tiles.
// ---------------------------------------------------------------------------
__global__ __launch_bounds__(256)
void wtrans(const float* __restrict__ W, unsigned short* __restrict__ WT,
            int K, int N)
{
    __shared__ float t[32][33];
    const int n0 = blockIdx.x * 32, k0 = blockIdx.y * 32;
    const int c = threadIdx.x & 31, r0 = threadIdx.x >> 5;
    #pragma unroll
    for (int rr = r0; rr < 32; rr += 8)
        t[rr][c] = W[(size_t)(k0 + rr) * N + n0 + c];
    __syncthreads();
    #pragma unroll
    for (int rr = r0; rr < 32; rr += 8)
        WT[(size_t)(n0 + rr) * K + k0 + c] = f2bf(t[c][rr]);
}

// ---------------------------------------------------------------------------
// LayerNorm over 256. One wave per row; optional bf16 copy output.
// ---------------------------------------------------------------------------
__global__ __launch_bounds__(256)
void ln_kernel(const float* __restrict__ X, const float* __restrict__ g,
               const float* __restrict__ bta, float* __restrict__ out,
               unsigned short* __restrict__ outb, int M)
{
    const int row  = blockIdx.x * 4 + (threadIdx.x >> 6);
    const int lane = threadIdx.x & 63;
    if (row >= M) return;
    const float4 v = ((const float4*)(X + (size_t)row * 256))[lane];
    float s  = v.x + v.y + v.z + v.w;
    float s2 = v.x * v.x + v.y * v.y + v.z * v.z + v.w * v.w;
    #pragma unroll
    for (int o = 32; o > 0; o >>= 1) {
        s  += __shfl_down(s,  o, 64);
        s2 += __shfl_down(s2, o, 64);
    }
    s  = __shfl(s,  0, 64);
    s2 = __shfl(s2, 0, 64);
    const float mean = s * (1.0f / 256.0f);
    const float var  = s2 * (1.0f / 256.0f) - mean * mean;
    const float r    = rsqrtf(var + 1e-5f);
    const float4 gg = ((const float4*)g)[lane];
    const float4 bb = ((const float4*)bta)[lane];
    float4 o4;
    o4.x = (v.x - mean) * r * gg.x + bb.x;
    o4.y = (v.y - mean) * r * gg.y + bb.y;
    o4.z = (v.z - mean) * r * gg.z + bb.z;
    o4.w = (v.w - mean) * r * gg.w + bb.w;
    ((float4*)(out + (size_t)row * 256))[lane] = o4;
    if (outb) {
        unsigned p0 = (unsigned)f2bf(o4.x) | ((unsigned)f2bf(o4.y) << 16);
        unsigned p1 = (unsigned)f2bf(o4.z) | ((unsigned)f2bf(o4.w) << 16);
        uint2 ob; ob.x = p0; ob.y = p1;
        *(uint2*)(outb + (size_t)row * 256 + lane * 4) = ob;
    }
}

// ---------------------------------------------------------------------------
// MSDA, 2-phase (unchanged from round 4).
// ---------------------------------------------------------------------------
__global__ __launch_bounds__(256)
void msda_kernel(const unsigned short* __restrict__ valb,
                 const float* __restrict__ oa,
                 const float* __restrict__ vr,
                 unsigned short* __restrict__ out)
{
    __shared__ __align__(16) char smeta[8 * 128 * 32];
    const int t = threadIdx.x;

    {
        const int wv = t >> 6, lane = t & 63;
        const int lqA = wv * 2 + (lane >> 5);
        const int bq = blockIdx.x * 8 + lqA;
        const int h = (lane >> 2) & 7;
        const int j = lane & 3;
        if (bq < M_TOT) {
            const int b = (bq >= S_TOT) ? 1 : 0;
            const int q = bq - b * S_TOT;
            int Hq, rr, cc;
            int lq;
            if (q < 10000)      { lq = 0; Hq = 100; rr = q / 100;              cc = q - rr * 100; }
            else if (q < 12500) { lq = 1; Hq = 50;  int r2 = q - 10000; rr = r2 / 50; cc = r2 - rr * 50; }
            else if (q < 13125) { lq = 2; Hq = 25;  int r2 = q - 12500; rr = r2 / 25; cc = r2 - rr * 25; }
            else                { lq = 3; Hq = 13;  int r2 = q - 13125; rr = r2 / 13; cc = r2 - rr * 13; }
            const float rxb = (cc + 0.5f) / (vr[(b * 4 + lq) * 2 + 0] * (float)Hq);
            const float ryb = (rr + 0.5f) / (vr[(b * 4 + lq) * 2 + 1] * (float)Hq);
            const int HWt[4] = {100, 50, 25, 13};
            const int stt[4] = {0, 10000, 12500, 13125};
            const int HW = HWt[j], st = stt[j];
            const float fW = (float)HW;
            const float refx = rxb * vr[(b * 4 + j) * 2 + 0];
            const float refy = ryb * vr[(b * 4 + j) * 2 + 1];
            const float* row = oa + (size_t)bq * 384;
            const float4 lg = *(const float4*)(row + 256 + h * 16 + j * 4);
            float mx = fmaxf(fmaxf(lg.x, lg.y), fmaxf(lg.z, lg.w));
            mx = fmaxf(mx, __shfl_xor(mx, 1, 64));
            mx = fmaxf(mx, __shfl_xor(mx, 2, 64));
            const float e0 = expf(lg.x - mx), e1 = expf(lg.y - mx);
            const float e2 = expf(lg.z - mx), e3 = expf(lg.w - mx);
            float ss = e0 + e1 + e2 + e3;
            ss += __shfl_xor(ss, 1, 64);
            ss += __shfl_xor(ss, 2, 64);
            const float inv = 1.0f / ss;
            const float4 oA = *(const float4*)(row + h * 32 + j * 8);
            const float4 oB = *(const float4*)(row + h * 32 + j * 8 + 4);
            const float oxs[4] = {oA.x, oA.z, oB.x, oB.z};
            const float oys[4] = {oA.y, oA.w, oB.y, oB.w};
            const float aw[4]  = {e0 * inv, e1 * inv, e2 * inv, e3 * inv};
            char* mb = smeta + (size_t)(lqA * 128 + h * 16 + j * 4) * 32;
            const int swz = ((h * 4 + j) & 7) << 4;
            #pragma unroll
            for (int p = 0; p < 4; ++p) {
                const float x = (refx + oxs[p] / fW) * fW - 0.5f;
                const float y = (refy + oys[p] / fW) * fW - 0.5f;
                const float x0f = floorf(x), y0f = floorf(y);
                const int x0 = (int)x0f, y0 = (int)y0f;
                const float fx = x - x0f, fy = y - y0f;
                const float wb[4] = {(1.f - fx) * (1.f - fy), fx * (1.f - fy),
                                     (1.f - fx) * fy,         fx * fy};
                const int xs[2] = {x0, x0 + 1};
                const int ys2[2] = {y0, y0 + 1};
                int iv[4]; float wv4[4];
                #pragma unroll
                for (int k = 0; k < 4; ++k) {
                    const int xi = xs[k & 1], yi = ys2[k >> 1];
                    const bool vld = ((unsigned)xi < (unsigned)HW) && ((unsigned)yi < (unsigned)HW);
                    const int xc = min(max(xi, 0), HW - 1);
                    const int yc = min(max(yi, 0), HW - 1);
                    iv[k] = ((st + yc * HW + xc) << 9) + (h << 6);
                    wv4[k] = vld ? wb[k] * aw[p] : 0.0f;
                }
                int4 i4; i4.x = iv[0]; i4.y = iv[1]; i4.z = iv[2]; i4.w = iv[3];
                float4 w4; w4.x = wv4[0]; w4.y = wv4[1]; w4.z = wv4[2]; w4.w = wv4[3];
                *(int4*)(mb + ((p * 32) ^ swz)) = i4;
                *(float4*)(mb + ((p * 32 + 16) ^ swz)) = w4;
            }
        }
    }
    __syncthreads();
    {
        const int lq2 = t >> 5;
        const int r = t & 31;
        const int h2 = r >> 2;
        const int cg = r & 3;
        const int bq2 = blockIdx.x * 8 + lq2;
        if (bq2 < M_TOT) {
            const int b2 = (bq2 >= S_TOT) ? 1 : 0;
            const char* vb = (const char*)valb + (size_t)b2 * ((size_t)S_TOT * 512) + cg * 16;
            float acc[8] = {0.f, 0.f, 0.f, 0.f, 0.f, 0.f, 0.f, 0.f};
            const char* mb2 = smeta + (size_t)(lq2 * 128 + h2 * 16) * 32;
            #pragma unroll 4
            for (int s = 0; s < 16; ++s) {
                const int swz2 = ((h2 * 4 + (s >> 2)) & 7) << 4;
                const int4  iv = *(const int4*)(mb2 + ((s * 32) ^ swz2));
                const float4 w4 = *(const float4*)(mb2 + ((s * 32 + 16) ^ swz2));
                const uint4 u0 = *(const uint4*)(vb + iv.x);
                const uint4 u1 = *(const uint4*)(vb + iv.y);
                const uint4 u2 = *(const uint4*)(vb + iv.z);
                const uint4 u3 = *(const uint4*)(vb + iv.w);
                #define ACC8(UU, WW) \
                    acc[0] = fmaf(WW, bflo(UU.x), acc[0]); acc[1] = fmaf(WW, bfhi(UU.x), acc[1]); \
                    acc[2] = fmaf(WW, bflo(UU.y), acc[2]); acc[3] = fmaf(WW, bfhi(UU.y), acc[3]); \
                    acc[4] = fmaf(WW, bflo(UU.z), acc[4]); acc[5] = fmaf(WW, bfhi(UU.z), acc[5]); \
                    acc[6] = fmaf(WW, bflo(UU.w), acc[6]); acc[7] = fmaf(WW, bfhi(UU.w), acc[7]);
                ACC8(u0, w4.x) ACC8(u1, w4.y) ACC8(u2, w4.z) ACC8(u3, w4.w)
                #undef ACC8
            }
            uint4 o;
            o.x = (unsigned)f2bf(acc[0]) | ((unsigned)f2bf(acc[1]) << 16);
            o.y = (unsigned)f2bf(acc[2]) | ((unsigned)f2bf(acc[3]) << 16);
            o.z = (unsigned)f2bf(acc[4]) | ((unsigned)f2bf(acc[5]) << 16);
            o.w = (unsigned)f2bf(acc[6]) | ((unsigned)f2bf(acc[7]) << 16);
            *(uint4*)(out + (size_t)bq2 * 256 + h2 * 32 + cg * 8) = o;
        }
    }
}

// ---------------------------------------------------------------------------
// Host-side orchestration
// ---------------------------------------------------------------------------
extern "C" void kernel_launch(void* const* d_in, const int* in_sizes, int n_in,
                              void* d_out, int out_size, void* d_ws, size_t ws_size,
                              hipStream_t stream)
{
    const float* src    = (const float*)d_in[0];
    const float* vr     = (const float*)d_in[2];
    const float* W_off  = (const float*)d_in[3];
    const float* b_off  = (const float*)d_in[4];
    const float* W_attn = (const float*)d_in[5];
    const float* b_attn = (const float*)d_in[6];
    const float* W_val  = (const float*)d_in[7];
    const float* b_val  = (const float*)d_in[8];
    const float* W_out  = (const float*)d_in[9];
    const float* b_out  = (const float*)d_in[10];
    const float* ln1_g  = (const float*)d_in[11];
    const float* ln1_b  = (const float*)d_in[12];
    const float* W1     = (const float*)d_in[13];
    const float* b1     = (const float*)d_in[14];
    const float* W2     = (const float*)d_in[15];
    const float* b2     = (const float*)d_in[16];
    const float* ln2_g  = (const float*)d_in[17];
    const float* ln2_b  = (const float*)d_in[18];
    float* out = (float*)d_out;

    const int M = M_TOT;

    // --- workspace (bytes), total 112,066,560 ---
    // [0,          40,894,464)  OA   f32 [M_PAD,384]    \ overlay: HBF bf16 [M_PAD,1024]
    // [40,894,464, 54,525,952)  VALB bf16 [M_PAD,256]   /
    // [54,525,952, 81,788,928)  T1   f32 [M_PAD,256]
    // [81,788,928, 95,420,416)  RB   bf16 [M_PAD,256]
    // [95,420,416,109,051,904)  YBF  bf16 [M_PAD,256]
    // [109,051,904,112,066,560) WT   bf16 transposed weights (both layers)
    char* wsb = (char*)d_ws;
    float*          OA   = (float*)wsb;
    unsigned short* VALB = (unsigned short*)(wsb + 40894464);
    unsigned short* HBF  = (unsigned short*)wsb;
    float*          T1   = (float*)(wsb + 54525952);
    unsigned short* RB   = (unsigned short*)(wsb + 81788928);
    unsigned short* YBF  = (unsigned short*)(wsb + 95420416);
    unsigned short* WT   = (unsigned short*)(wsb + 109051904);

    const size_t LWT = 753664;
    // merged projection WT[640,256]: rows 0-255 W_val^T, 256-511 W_off^T, 512-639 W_attn^T
    const size_t oProj = 0, oOut = 163840, oW1 = 229376, oW2 = 491520;

    for (int i = 0; i < 2; ++i) {
        unsigned short* wt = WT + i * LWT;
        wtrans<<<dim3(8, 8),  256, 0, stream>>>(W_val  + i * 65536,  wt + oProj,          256, 256);
        wtrans<<<dim3(8, 8),  256, 0, stream>>>(W_off  + i * 65536,  wt + oProj + 65536,  256, 256);
        wtrans<<<dim3(4, 8),  256, 0, stream>>>(W_attn + i * 32768,  wt + oProj + 131072, 256, 128);
        wtrans<<<dim3(8, 8),  256, 0, stream>>>(W_out  + i * 65536,  wt + oOut,           256, 256);
        wtrans<<<dim3(32, 8), 256, 0, stream>>>(W1     + i * 262144, wt + oW1,            256, 1024);
        wtrans<<<dim3(8, 32), 256, 0, stream>>>(W2     + i * 262144, wt + oW2,            1024, 256);
    }

    const int GM128 = M_PAD / 128;  // 208
    const int GM64  = M_PAD / 64;   // 416
    const dim3 blk(256);

    for (int i = 0; i < 2; ++i) {
        const float* xin = (i == 0) ? src : out;
        unsigned short* wt = WT + i * LWT;

        if (i == 0)
            convpad<<<dim3(M_PAD / 4), blk, 0, stream>>>(src, RB, M);

        // merged projections: N=640 -> VALB (bf16, cols<256) + OA (f32, cols>=256)
        mgemm<64, false, false, false, false, true><<<dim3(5, GM64), blk, 0, stream>>>(
            RB, wt + oProj, b_val + i * 256, b_off + i * 256, b_attn + i * 128,
            nullptr, OA, VALB, M, 640, 256);

        // deformable sampling (2-phase), writes bf16
        msda_kernel<<<dim3((M + 7) / 8), blk, 0, stream>>>(VALB, OA, vr, YBF);

        // out-proj + residual -> T1 (f32), LN1 -> T1 + bf16 RB
        mgemm<64, false, true, true, false, false><<<dim3(2, GM64), blk, 0, stream>>>(
            YBF, wt + oOut, b_out + i * 256, nullptr, nullptr,
            xin, T1, nullptr, M, 256, 256);
        ln_kernel<<<dim3((M + 3) / 4), blk, 0, stream>>>(
            T1, ln1_g + i * 256, ln1_b + i * 256, T1, RB, M);

        // FFN1 (relu, bf16 hidden overlays OA+VALB)
        mgemm<128, true, false, false, true, false><<<dim3(8, GM128), blk, 0, stream>>>(
            RB, wt + oW1, b1 + i * 1024, nullptr, nullptr,
            nullptr, nullptr, HBF, M, 1024, 256);

        // FFN2 + residual (in-place T1)
        mgemm<64, false, true, true, false, false><<<dim3(2, GM64), blk, 0, stream>>>(
            HBF, wt + oW2, b2 + i * 256, nullptr, nullptr,
            T1, T1, nullptr, M, 256, 1024);

        // LN2 -> out (+ bf16 RB for next layer when i==0)
        ln_kernel<<<dim3((M + 3) / 4), blk, 0, stream>>>(
            T1, ln2_g + i * 256, ln2_b + i * 256, out, (i == 0) ? RB : nullptr, M);
    }
}

// Round 7
// 456.608 us; speedup vs baseline: 1.5499x; 1.1306x over previous
//
#include <hip/hip_runtime.h>
#include <math.h>

// Deformable-DETR encoder, 2 layers. Round 7: BK=64 GEMM loops, LN fused into
// N=256 GEMMs (LDS-staged tiles + cross-wave LN reduction), merged wtrans.

#define S_TOT 13294
#define BATCH 2
#define M_TOT (BATCH * S_TOT)     // 26588
#define M_PAD 26624               // 208 * 128 = 416 * 64

typedef __attribute__((ext_vector_type(8))) short short8;
typedef __attribute__((ext_vector_type(4))) float floatx4;

#define AS1C(p) ((const __attribute__((address_space(1))) void*)(p))
#define AS3(p)  ((__attribute__((address_space(3))) void*)(p))

static __device__ __forceinline__ unsigned short f2bf(float x) {
    union { float f; unsigned u; } v; v.f = x;
    unsigned r = v.u + 0x7FFFu + ((v.u >> 16) & 1u);
    return (unsigned short)(r >> 16);
}
static __device__ __forceinline__ float bflo(unsigned u) {
    union { unsigned u; float f; } v; v.u = u << 16; return v.f;
}
static __device__ __forceinline__ float bfhi(unsigned u) {
    union { unsigned u; float f; } v; v.u = u & 0xFFFF0000u; return v.f;
}

// ---------------------------------------------------------------------------
// bf16 MFMA GEMM, BK=64 (two 32-chunks per barrier pair).
// TM=128: 4 waves 2x2 of 64x64. TM=64: 4 waves of 64x32.
// PROJ epilogue: col<256 -> bf16 Cb[.,256]; col>=256 -> f32 Cf[.,384].
// ---------------------------------------------------------------------------
template<int TM, bool RELU, bool RES, bool F32OUT, bool BF16OUT, bool PROJ>
__global__ __launch_bounds__(256)
void mgemm(const unsigned short* __restrict__ A,
           const unsigned short* __restrict__ BT,
           const float* __restrict__ bias,
           const float* __restrict__ bias2,
           const float* __restrict__ bias3,
           const float* __restrict__ R,
           float* __restrict__ Cf,
           unsigned short* __restrict__ Cb,
           int M, int N, int K)
{
    constexpr int WM = (TM == 128) ? 2 : 1;
    constexpr int WN = 4 / WM;
    constexpr int MI = TM / (WM * 16);    // 4
    constexpr int NI = 128 / (WN * 16);   // 4 (TM=128) or 2 (TM=64)
    __shared__ __align__(16) unsigned short smemA[2 * TM * 32];
    __shared__ __align__(16) unsigned short smemB[2 * 128 * 32];
    const int tid  = threadIdx.x;
    const int lane = tid & 63;
    const int w    = tid >> 6;
    const int wm   = w % WM, wn = w / WM;
    const int lr   = lane & 15, quad = lane >> 4;
    const int bm   = blockIdx.y * TM;
    const int bn   = blockIdx.x * 128;

    floatx4 acc[MI][NI];
    #pragma unroll
    for (int i = 0; i < MI; ++i)
        #pragma unroll
        for (int j = 0; j < NI; ++j)
            acc[i][j] = (floatx4){0.f, 0.f, 0.f, 0.f};

    const int srow = lane >> 2;
    const int selt = (lane & 3) << 3;

    for (int k0 = 0; k0 < K; k0 += 64) {
        #pragma unroll
        for (int c = 0; c < 2; ++c) {
            if (TM == 128) {
                #pragma unroll
                for (int jj = 0; jj < 2; ++jj) {
                    const int j = 2 * w + jj;
                    const unsigned short* ga = A  + (size_t)(bm + j * 16 + srow) * K + k0 + c * 32 + selt;
                    const unsigned short* gb = BT + (size_t)(bn + j * 16 + srow) * K + k0 + c * 32 + selt;
                    __builtin_amdgcn_global_load_lds(AS1C(ga), AS3(smemA + c * (TM * 32) + j * 512), 16, 0, 0);
                    __builtin_amdgcn_global_load_lds(AS1C(gb), AS3(smemB + c * 4096 + j * 512), 16, 0, 0);
                }
            } else {
                const unsigned short* ga = A + (size_t)(bm + w * 16 + srow) * K + k0 + c * 32 + selt;
                __builtin_amdgcn_global_load_lds(AS1C(ga), AS3(smemA + c * (TM * 32) + w * 512), 16, 0, 0);
                #pragma unroll
                for (int jj = 0; jj < 2; ++jj) {
                    const int j = 2 * w + jj;
                    const unsigned short* gb = BT + (size_t)(bn + j * 16 + srow) * K + k0 + c * 32 + selt;
                    __builtin_amdgcn_global_load_lds(AS1C(gb), AS3(smemB + c * 4096 + j * 512), 16, 0, 0);
                }
            }
        }
        __syncthreads();

        #pragma unroll
        for (int c = 0; c < 2; ++c) {
            short8 av[MI], bv[NI];
            #pragma unroll
            for (int mi = 0; mi < MI; ++mi)
                av[mi] = *(const short8*)&smemA[c * (TM * 32) + (wm * MI * 16 + mi * 16 + lr) * 32 + quad * 8];
            #pragma unroll
            for (int ni = 0; ni < NI; ++ni)
                bv[ni] = *(const short8*)&smemB[c * 4096 + (wn * NI * 16 + ni * 16 + lr) * 32 + quad * 8];
            #pragma unroll
            for (int mi = 0; mi < MI; ++mi)
                #pragma unroll
                for (int ni = 0; ni < NI; ++ni)
                    acc[mi][ni] = __builtin_amdgcn_mfma_f32_16x16x32_bf16(
                        av[mi], bv[ni], acc[mi][ni], 0, 0, 0);
        }
        __syncthreads();
    }

    #pragma unroll
    for (int mi = 0; mi < MI; ++mi) {
        #pragma unroll
        for (int ni = 0; ni < NI; ++ni) {
            #pragma unroll
            for (int r = 0; r < 4; ++r) {
                const int row = bm + wm * MI * 16 + mi * 16 + quad * 4 + r;
                const int col = bn + wn * NI * 16 + ni * 16 + lr;
                if (PROJ) {
                    const float bb = (col < 256) ? bias[col]
                                   : (col < 512) ? bias2[col - 256]
                                                 : bias3[col - 512];
                    const float v = acc[mi][ni][r] + bb;
                    if (col < 256) Cb[(size_t)row * 256 + col] = f2bf(v);
                    else           Cf[(size_t)row * 384 + (col - 256)] = v;
                } else {
                    float v = acc[mi][ni][r] + bias[col];
                    if (RES) { if (row < M) v += R[(size_t)row * N + col]; }
                    if (RELU) v = fmaxf(v, 0.0f);
                    if (F32OUT) Cf[(size_t)row * N + col] = v;
                    if (BF16OUT) Cb[(size_t)row * N + col] = f2bf(v);
                }
            }
        }
    }
}

// ---------------------------------------------------------------------------
// Fused GEMM(N=256, LDS-staged) + bias + residual + LayerNorm.
// Tile 64 rows x 256 cols; wave w owns cols [w*64, +64) (MI=4, NI=4).
// LN: per-wave row partials -> shfl_xor over lr -> LDS [row][8] -> reduce.
// ---------------------------------------------------------------------------
template<bool HASB>
__global__ __launch_bounds__(256)
void mgemm_ln(const unsigned short* __restrict__ A,
              const unsigned short* __restrict__ BT,
              const float* __restrict__ bias,
              const float* __restrict__ R,
              const float* __restrict__ g,
              const float* __restrict__ beta,
              float* __restrict__ outF,
              unsigned short* __restrict__ outB,
              int M, int K)
{
    __shared__ __align__(16) unsigned short smemA[2 * 64 * 32];    // 8 KB
    __shared__ __align__(16) unsigned short smemB[2 * 256 * 32];   // 32 KB
    const int lane = threadIdx.x & 63;
    const int w    = threadIdx.x >> 6;
    const int lr   = lane & 15, quad = lane >> 4;
    const int bm   = blockIdx.x * 64;
    const int srow = lane >> 2;
    const int selt = (lane & 3) << 3;

    floatx4 acc[4][4];
    #pragma unroll
    for (int i = 0; i < 4; ++i)
        #pragma unroll
        for (int j = 0; j < 4; ++j)
            acc[i][j] = (floatx4){0.f, 0.f, 0.f, 0.f};

    for (int k0 = 0; k0 < K; k0 += 64) {
        #pragma unroll
        for (int c = 0; c < 2; ++c) {
            const unsigned short* ga = A + (size_t)(bm + w * 16 + srow) * K + k0 + c * 32 + selt;
            __builtin_amdgcn_global_load_lds(AS1C(ga), AS3(smemA + c * 2048 + w * 512), 16, 0, 0);
            #pragma unroll
            for (int jj = 0; jj < 4; ++jj) {
                const int j = 4 * w + jj;
                const unsigned short* gb = BT + (size_t)(j * 16 + srow) * K + k0 + c * 32 + selt;
                __builtin_amdgcn_global_load_lds(AS1C(gb), AS3(smemB + c * 8192 + j * 512), 16, 0, 0);
            }
        }
        __syncthreads();
        #pragma unroll
        for (int c = 0; c < 2; ++c) {
            short8 av[4], bv[4];
            #pragma unroll
            for (int mi = 0; mi < 4; ++mi)
                av[mi] = *(const short8*)&smemA[c * 2048 + (mi * 16 + lr) * 32 + quad * 8];
            #pragma unroll
            for (int ni = 0; ni < 4; ++ni)
                bv[ni] = *(const short8*)&smemB[c * 8192 + (w * 64 + ni * 16 + lr) * 32 + quad * 8];
            #pragma unroll
            for (int mi = 0; mi < 4; ++mi)
                #pragma unroll
                for (int ni = 0; ni < 4; ++ni)
                    acc[mi][ni] = __builtin_amdgcn_mfma_f32_16x16x32_bf16(
                        av[mi], bv[ni], acc[mi][ni], 0, 0, 0);
        }
        __syncthreads();
    }

    float bs[4], gs[4], bts[4];
    #pragma unroll
    for (int ni = 0; ni < 4; ++ni) {
        const int col = w * 64 + ni * 16 + lr;
        bs[ni] = bias[col]; gs[ni] = g[col]; bts[ni] = beta[col];
    }
    float* lnbuf = (float*)smemA;   // 64 rows x 8 floats = 2 KB (reuse)

    #pragma unroll
    for (int mi = 0; mi < 4; ++mi) {
        #pragma unroll
        for (int r = 0; r < 4; ++r) {
            const int rl = mi * 16 + quad * 4 + r;
            const int grow = bm + rl;
            const bool act = grow < M;
            float p = 0.f, q = 0.f;
            #pragma unroll
            for (int ni = 0; ni < 4; ++ni) {
                const int col = w * 64 + ni * 16 + lr;
                const float rv = act ? R[(size_t)grow * 256 + col] : 0.f;
                const float x = acc[mi][ni][r] + bs[ni] + rv;
                acc[mi][ni][r] = x;
                p += x; q += x * x;
            }
            #pragma unroll
            for (int o = 1; o < 16; o <<= 1) {
                p += __shfl_xor(p, o, 64);
                q += __shfl_xor(q, o, 64);
            }
            if (lr == 0) {
                lnbuf[rl * 8 + 2 * w]     = p;
                lnbuf[rl * 8 + 2 * w + 1] = q;
            }
        }
    }
    __syncthreads();
    #pragma unroll
    for (int mi = 0; mi < 4; ++mi) {
        #pragma unroll
        for (int r = 0; r < 4; ++r) {
            const int rl = mi * 16 + quad * 4 + r;
            const int grow = bm + rl;
            const float4 pa = *(const float4*)&lnbuf[rl * 8];
            const float4 pb = *(const float4*)&lnbuf[rl * 8 + 4];
            const float s  = pa.x + pa.z + pb.x + pb.z;
            const float s2 = pa.y + pa.w + pb.y + pb.w;
            const float mean = s * (1.0f / 256.0f);
            const float var  = s2 * (1.0f / 256.0f) - mean * mean;
            const float rs   = rsqrtf(var + 1e-5f);
            if (grow < M) {
                #pragma unroll
                for (int ni = 0; ni < 4; ++ni) {
                    const int col = w * 64 + ni * 16 + lr;
                    const float y = (acc[mi][ni][r] - mean) * rs * gs[ni] + bts[ni];
                    outF[(size_t)grow * 256 + col] = y;
                    if (HASB) outB[(size_t)grow * 256 + col] = f2bf(y);
                }
            }
        }
    }
}

// ---------------------------------------------------------------------------
// fp32 [M,256] -> bf16 [M_PAD,256] with zero padding rows (layer 0 only)
// ---------------------------------------------------------------------------
__global__ __launch_bounds__(256)
void convpad(const float* __restrict__ X, unsigned short* __restrict__ Y, int M)
{
    const int idx = blockIdx.x * 256 + threadIdx.x;
    const int row = idx >> 6;
    const int c4  = (idx & 63) << 2;
    if (row >= M_PAD) return;
    float4 v = {0.f, 0.f, 0.f, 0.f};
    if (row < M) v = ((const float4*)(X + (size_t)row * 256))[c4 >> 2];
    unsigned p0 = (unsigned)f2bf(v.x) | ((unsigned)f2bf(v.y) << 16);
    unsigned p1 = (unsigned)f2bf(v.z) | ((unsigned)f2bf(v.w) << 16);
    uint2 o; o.x = p0; o.y = p1;
    *(uint2*)(Y + (size_t)row * 256 + c4) = o;
}

// ---------------------------------------------------------------------------
// Merged weight transpose+convert: all 12 W[K,N] f32 -> WT[N,K] bf16 in one
// dispatch. Block -> (segment, 32x32 tile) via descriptor table.
// ---------------------------------------------------------------------------
struct WJobs {
    const float* W[12];
    unsigned short* WT[12];
    int K[12], N[12], tx[12], start[12];
};

__global__ __launch_bounds__(256)
void wtrans_all(WJobs jb)
{
    __shared__ float t[32][33];
    const int bx = blockIdx.x;
    int seg = 0;
    #pragma unroll
    for (int s = 1; s < 12; ++s) if (bx >= jb.start[s]) seg = s;
    const float* W = jb.W[seg];
    unsigned short* WT = jb.WT[seg];
    const int K = jb.K[seg], N = jb.N[seg], tx = jb.tx[seg];
    const int local = bx - jb.start[seg];
    const int n0 = (local % tx) * 32, k0 = (local / tx) * 32;
    const int c = threadIdx.x & 31, r0 = threadIdx.x >> 5;
    #pragma unroll
    for (int rr = r0; rr < 32; rr += 8)
        t[rr][c] = W[(size_t)(k0 + rr) * N + n0 + c];
    __syncthreads();
    #pragma unroll
    for (int rr = r0; rr < 32; rr += 8)
        WT[(size_t)(n0 + rr) * K + k0 + c] = f2bf(t[c][rr]);
}

// ---------------------------------------------------------------------------
// MSDA, 2-phase. Batch slab folded into phase-A byte offsets (saddr gathers).
// ---------------------------------------------------------------------------
__global__ __launch_bounds__(256)
void msda_kernel(const unsigned short* __restrict__ valb,
                 const float* __restrict__ oa,
                 const float* __restrict__ vr,
                 unsigned short* __restrict__ out)
{
    __shared__ __align__(16) char smeta[8 * 128 * 32];
    const int t = threadIdx.x;

    {
        const int wv = t >> 6, lane = t & 63;
        const int lqA = wv * 2 + (lane >> 5);
        const int bq = blockIdx.x * 8 + lqA;
        const int h = (lane >> 2) & 7;
        const int j = lane & 3;
        if (bq < M_TOT) {
            const int b = (bq >= S_TOT) ? 1 : 0;
            const int q = bq - b * S_TOT;
            const int bofs = b * (S_TOT * 512);
            int Hq, rr, cc;
            int lq;
            if (q < 10000)      { lq = 0; Hq = 100; rr = q / 100;              cc = q - rr * 100; }
            else if (q < 12500) { lq = 1; Hq = 50;  int r2 = q - 10000; rr = r2 / 50; cc = r2 - rr * 50; }
            else if (q < 13125) { lq = 2; Hq = 25;  int r2 = q - 12500; rr = r2 / 25; cc = r2 - rr * 25; }
            else                { lq = 3; Hq = 13;  int r2 = q - 13125; rr = r2 / 13; cc = r2 - rr * 13; }
            const float rxb = (cc + 0.5f) / (vr[(b * 4 + lq) * 2 + 0] * (float)Hq);
            const float ryb = (rr + 0.5f) / (vr[(b * 4 + lq) * 2 + 1] * (float)Hq);
            const int HWt[4] = {100, 50, 25, 13};
            const int stt[4] = {0, 10000, 12500, 13125};
            const int HW = HWt[j], st = stt[j];
            const float fW = (float)HW;
            const float refx = rxb * vr[(b * 4 + j) * 2 + 0];
            const float refy = ryb * vr[(b * 4 + j) * 2 + 1];
            const float* row = oa + (size_t)bq * 384;
            const float4 lg = *(const float4*)(row + 256 + h * 16 + j * 4);
            float mx = fmaxf(fmaxf(lg.x, lg.y), fmaxf(lg.z, lg.w));
            mx = fmaxf(mx, __shfl_xor(mx, 1, 64));
            mx = fmaxf(mx, __shfl_xor(mx, 2, 64));
            const float e0 = expf(lg.x - mx), e1 = expf(lg.y - mx);
            const float e2 = expf(lg.z - mx), e3 = expf(lg.w - mx);
            float ss = e0 + e1 + e2 + e3;
            ss += __shfl_xor(ss, 1, 64);
            ss += __shfl_xor(ss, 2, 64);
            const float inv = 1.0f / ss;
            const float4 oA = *(const float4*)(row + h * 32 + j * 8);
            const float4 oB = *(const float4*)(row + h * 32 + j * 8 + 4);
            const float oxs[4] = {oA.x, oA.z, oB.x, oB.z};
            const float oys[4] = {oA.y, oA.w, oB.y, oB.w};
            const float aw[4]  = {e0 * inv, e1 * inv, e2 * inv, e3 * inv};
            char* mb = smeta + (size_t)(lqA * 128 + h * 16 + j * 4) * 32;
            const int swz = ((h * 4 + j) & 7) << 4;
            #pragma unroll
            for (int p = 0; p < 4; ++p) {
                const float x = (refx + oxs[p] / fW) * fW - 0.5f;
                const float y = (refy + oys[p] / fW) * fW - 0.5f;
                const float x0f = floorf(x), y0f = floorf(y);
                const int x0 = (int)x0f, y0 = (int)y0f;
                const float fx = x - x0f, fy = y - y0f;
                const float wb[4] = {(1.f - fx) * (1.f - fy), fx * (1.f - fy),
                                     (1.f - fx) * fy,         fx * fy};
                const int xs[2] = {x0, x0 + 1};
                const int ys2[2] = {y0, y0 + 1};
                int iv[4]; float wv4[4];
                #pragma unroll
                for (int k = 0; k < 4; ++k) {
                    const int xi = xs[k & 1], yi = ys2[k >> 1];
                    const bool vld = ((unsigned)xi < (unsigned)HW) && ((unsigned)yi < (unsigned)HW);
                    const int xc = min(max(xi, 0), HW - 1);
                    const int yc = min(max(yi, 0), HW - 1);
                    iv[k] = bofs + ((st + yc * HW + xc) << 9) + (h << 6);
                    wv4[k] = vld ? wb[k] * aw[p] : 0.0f;
                }
                int4 i4; i4.x = iv[0]; i4.y = iv[1]; i4.z = iv[2]; i4.w = iv[3];
                float4 w4; w4.x = wv4[0]; w4.y = wv4[1]; w4.z = wv4[2]; w4.w = wv4[3];
                *(int4*)(mb + ((p * 32) ^ swz)) = i4;
                *(float4*)(mb + ((p * 32 + 16) ^ swz)) = w4;
            }
        }
    }
    __syncthreads();
    {
        const int lq2 = t >> 5;
        const int r = t & 31;
        const int h2 = r >> 2;
        const int cg = r & 3;
        const int bq2 = blockIdx.x * 8 + lq2;
        if (bq2 < M_TOT) {
            const char* vbase = (const char*)valb;
            const unsigned cgo = cg * 16;
            float acc[8] = {0.f, 0.f, 0.f, 0.f, 0.f, 0.f, 0.f, 0.f};
            const char* mb2 = smeta + (size_t)(lq2 * 128 + h2 * 16) * 32;
            #pragma unroll 4
            for (int s = 0; s < 16; ++s) {
                const int swz2 = ((h2 * 4 + (s >> 2)) & 7) << 4;
                const int4  iv = *(const int4*)(mb2 + ((s * 32) ^ swz2));
                const float4 w4 = *(const float4*)(mb2 + ((s * 32 + 16) ^ swz2));
                const uint4 u0 = *(const uint4*)(vbase + (unsigned)(iv.x + cgo));
                const uint4 u1 = *(const uint4*)(vbase + (unsigned)(iv.y + cgo));
                const uint4 u2 = *(const uint4*)(vbase + (unsigned)(iv.z + cgo));
                const uint4 u3 = *(const uint4*)(vbase + (unsigned)(iv.w + cgo));
                #define ACC8(UU, WW) \
                    acc[0] = fmaf(WW, bflo(UU.x), acc[0]); acc[1] = fmaf(WW, bfhi(UU.x), acc[1]); \
                    acc[2] = fmaf(WW, bflo(UU.y), acc[2]); acc[3] = fmaf(WW, bfhi(UU.y), acc[3]); \
                    acc[4] = fmaf(WW, bflo(UU.z), acc[4]); acc[5] = fmaf(WW, bfhi(UU.z), acc[5]); \
                    acc[6] = fmaf(WW, bflo(UU.w), acc[6]); acc[7] = fmaf(WW, bfhi(UU.w), acc[7]);
                ACC8(u0, w4.x) ACC8(u1, w4.y) ACC8(u2, w4.z) ACC8(u3, w4.w)
                #undef ACC8
            }
            uint4 o;
            o.x = (unsigned)f2bf(acc[0]) | ((unsigned)f2bf(acc[1]) << 16);
            o.y = (unsigned)f2bf(acc[2]) | ((unsigned)f2bf(acc[3]) << 16);
            o.z = (unsigned)f2bf(acc[4]) | ((unsigned)f2bf(acc[5]) << 16);
            o.w = (unsigned)f2bf(acc[6]) | ((unsigned)f2bf(acc[7]) << 16);
            *(uint4*)(out + (size_t)bq2 * 256 + h2 * 32 + cg * 8) = o;
        }
    }
}

// ---------------------------------------------------------------------------
// Host-side orchestration
// ---------------------------------------------------------------------------
extern "C" void kernel_launch(void* const* d_in, const int* in_sizes, int n_in,
                              void* d_out, int out_size, void* d_ws, size_t ws_size,
                              hipStream_t stream)
{
    const float* src    = (const float*)d_in[0];
    const float* vr     = (const float*)d_in[2];
    const float* W_off  = (const float*)d_in[3];
    const float* b_off  = (const float*)d_in[4];
    const float* W_attn = (const float*)d_in[5];
    const float* b_attn = (const float*)d_in[6];
    const float* W_val  = (const float*)d_in[7];
    const float* b_val  = (const float*)d_in[8];
    const float* W_out  = (const float*)d_in[9];
    const float* b_out  = (const float*)d_in[10];
    const float* ln1_g  = (const float*)d_in[11];
    const float* ln1_b  = (const float*)d_in[12];
    const float* W1     = (const float*)d_in[13];
    const float* b1     = (const float*)d_in[14];
    const float* W2     = (const float*)d_in[15];
    const float* b2     = (const float*)d_in[16];
    const float* ln2_g  = (const float*)d_in[17];
    const float* ln2_b  = (const float*)d_in[18];
    float* out = (float*)d_out;

    const int M = M_TOT;

    // --- workspace (bytes), total 112,066,560 ---
    char* wsb = (char*)d_ws;
    float*          OA   = (float*)wsb;                          // [M_PAD,384] f32
    unsigned short* VALB = (unsigned short*)(wsb + 40894464);    // [M_PAD,256] bf16
    unsigned short* HBF  = (unsigned short*)wsb;                 // [M_PAD,1024] bf16 (overlay)
    float*          T1   = (float*)(wsb + 54525952);             // [M_PAD,256] f32 post-LN1
    unsigned short* RB   = (unsigned short*)(wsb + 81788928);    // [M_PAD,256] bf16
    unsigned short* YBF  = (unsigned short*)(wsb + 95420416);    // [M_PAD,256] bf16
    unsigned short* WT   = (unsigned short*)(wsb + 109051904);   // transposed weights

    const size_t LWT = 753664;
    const size_t oProj = 0, oOut = 163840, oW1 = 229376, oW2 = 491520;

    // merged weight transposes: one dispatch for all 12 segments
    WJobs jb;
    int startAcc = 0;
    for (int i = 0; i < 2; ++i) {
        unsigned short* wt = WT + i * LWT;
        const float* srcs[6] = {W_val + i * 65536, W_off + i * 65536, W_attn + i * 32768,
                                W_out + i * 65536, W1 + i * 262144, W2 + i * 262144};
        unsigned short* dsts[6] = {wt + oProj, wt + oProj + 65536, wt + oProj + 131072,
                                   wt + oOut, wt + oW1, wt + oW2};
        const int Ks[6] = {256, 256, 256, 256, 256, 1024};
        const int Ns[6] = {256, 256, 128, 256, 1024, 256};
        for (int s = 0; s < 6; ++s) {
            const int idx = i * 6 + s;
            jb.W[idx] = srcs[s]; jb.WT[idx] = dsts[s];
            jb.K[idx] = Ks[s]; jb.N[idx] = Ns[s]; jb.tx[idx] = Ns[s] / 32;
            jb.start[idx] = startAcc;
            startAcc += (Ns[s] / 32) * (Ks[s] / 32);
        }
    }
    wtrans_all<<<dim3(startAcc), 256, 0, stream>>>(jb);

    const int GM128 = M_PAD / 128;  // 208
    const int GM64  = M_PAD / 64;   // 416
    const dim3 blk(256);

    for (int i = 0; i < 2; ++i) {
        const float* xin = (i == 0) ? src : out;
        unsigned short* wt = WT + i * LWT;

        if (i == 0)
            convpad<<<dim3(M_PAD / 4), blk, 0, stream>>>(src, RB, M);

        // merged projections: N=640 -> VALB (bf16) + OA (f32)
        mgemm<64, false, false, false, false, true><<<dim3(5, GM64), blk, 0, stream>>>(
            RB, wt + oProj, b_val + i * 256, b_off + i * 256, b_attn + i * 128,
            nullptr, OA, VALB, M, 640, 256);

        // deformable sampling
        msda_kernel<<<dim3((M + 7) / 8), blk, 0, stream>>>(VALB, OA, vr, YBF);

        // fused out-proj + residual(xin) + LN1 -> T1 (f32) + RB (bf16)
        mgemm_ln<true><<<dim3(GM64), blk, 0, stream>>>(
            YBF, wt + oOut, b_out + i * 256, xin,
            ln1_g + i * 256, ln1_b + i * 256, T1, RB, M, 256);

        // FFN1 (relu, bf16 hidden overlays OA+VALB)
        mgemm<128, true, false, false, true, false><<<dim3(8, GM128), blk, 0, stream>>>(
            RB, wt + oW1, b1 + i * 1024, nullptr, nullptr,
            nullptr, nullptr, HBF, M, 1024, 256);

        // fused FFN2 + residual(T1) + LN2 -> out (f32) [+ RB bf16 on layer 0]
        if (i == 0)
            mgemm_ln<true><<<dim3(GM64), blk, 0, stream>>>(
                HBF, wt + oW2, b2 + i * 256, T1,
                ln2_g + i * 256, ln2_b + i * 256, out, RB, M, 1024);
        else
            mgemm_ln<false><<<dim3(GM64), blk, 0, stream>>>(
                HBF, wt + oW2, b2 + i * 256, T1,
                ln2_g + i * 256, ln2_b + i * 256, out, nullptr, M, 1024);
    }
}

// Round 8
// 455.481 us; speedup vs baseline: 1.5538x; 1.0025x over previous
//
#include <hip/hip_runtime.h>
#include <math.h>

// Deformable-DETR encoder, 2 layers. Round 8: msda VALU diet (no divides,
// __expf, bf16 off/attn, packed fma), mgemm_ln 32-row tiles (2x grid).

#define S_TOT 13294
#define BATCH 2
#define M_TOT (BATCH * S_TOT)     // 26588
#define M_PAD 26624               // 208*128 = 416*64 = 832*32

typedef __attribute__((ext_vector_type(8))) short short8;
typedef __attribute__((ext_vector_type(4))) float floatx4;
typedef __attribute__((ext_vector_type(2))) float floatx2;

#define AS1C(p) ((const __attribute__((address_space(1))) void*)(p))
#define AS3(p)  ((__attribute__((address_space(3))) void*)(p))

static __device__ __forceinline__ unsigned short f2bf(float x) {
    union { float f; unsigned u; } v; v.f = x;
    unsigned r = v.u + 0x7FFFu + ((v.u >> 16) & 1u);
    return (unsigned short)(r >> 16);
}
static __device__ __forceinline__ float bflo(unsigned u) {
    union { unsigned u; float f; } v; v.u = u << 16; return v.f;
}
static __device__ __forceinline__ float bfhi(unsigned u) {
    union { unsigned u; float f; } v; v.u = u & 0xFFFF0000u; return v.f;
}

// ---------------------------------------------------------------------------
// bf16 MFMA GEMM, BK=64. TM=128: 4 waves 2x2 of 64x64. TM=64: 4 waves 64x32.
// PROJ epilogue: col<256 -> bf16 Cb[.,256]; col>=256 -> bf16 Cb2[.,384].
// ---------------------------------------------------------------------------
template<int TM, bool RELU, bool RES, bool F32OUT, bool BF16OUT, bool PROJ>
__global__ __launch_bounds__(256)
void mgemm(const unsigned short* __restrict__ A,
           const unsigned short* __restrict__ BT,
           const float* __restrict__ bias,
           const float* __restrict__ bias2,
           const float* __restrict__ bias3,
           const float* __restrict__ R,
           float* __restrict__ Cf,
           unsigned short* __restrict__ Cb,
           unsigned short* __restrict__ Cb2,
           int M, int N, int K)
{
    constexpr int WM = (TM == 128) ? 2 : 1;
    constexpr int WN = 4 / WM;
    constexpr int MI = TM / (WM * 16);
    constexpr int NI = 128 / (WN * 16);
    __shared__ __align__(16) unsigned short smemA[2 * TM * 32];
    __shared__ __align__(16) unsigned short smemB[2 * 128 * 32];
    const int tid  = threadIdx.x;
    const int lane = tid & 63;
    const int w    = tid >> 6;
    const int wm   = w % WM, wn = w / WM;
    const int lr   = lane & 15, quad = lane >> 4;
    const int bm   = blockIdx.y * TM;
    const int bn   = blockIdx.x * 128;

    floatx4 acc[MI][NI];
    #pragma unroll
    for (int i = 0; i < MI; ++i)
        #pragma unroll
        for (int j = 0; j < NI; ++j)
            acc[i][j] = (floatx4){0.f, 0.f, 0.f, 0.f};

    const int srow = lane >> 2;
    const int selt = (lane & 3) << 3;

    for (int k0 = 0; k0 < K; k0 += 64) {
        #pragma unroll
        for (int c = 0; c < 2; ++c) {
            if (TM == 128) {
                #pragma unroll
                for (int jj = 0; jj < 2; ++jj) {
                    const int j = 2 * w + jj;
                    const unsigned short* ga = A  + (size_t)(bm + j * 16 + srow) * K + k0 + c * 32 + selt;
                    const unsigned short* gb = BT + (size_t)(bn + j * 16 + srow) * K + k0 + c * 32 + selt;
                    __builtin_amdgcn_global_load_lds(AS1C(ga), AS3(smemA + c * (TM * 32) + j * 512), 16, 0, 0);
                    __builtin_amdgcn_global_load_lds(AS1C(gb), AS3(smemB + c * 4096 + j * 512), 16, 0, 0);
                }
            } else {
                const unsigned short* ga = A + (size_t)(bm + w * 16 + srow) * K + k0 + c * 32 + selt;
                __builtin_amdgcn_global_load_lds(AS1C(ga), AS3(smemA + c * (TM * 32) + w * 512), 16, 0, 0);
                #pragma unroll
                for (int jj = 0; jj < 2; ++jj) {
                    const int j = 2 * w + jj;
                    const unsigned short* gb = BT + (size_t)(bn + j * 16 + srow) * K + k0 + c * 32 + selt;
                    __builtin_amdgcn_global_load_lds(AS1C(gb), AS3(smemB + c * 4096 + j * 512), 16, 0, 0);
                }
            }
        }
        __syncthreads();

        #pragma unroll
        for (int c = 0; c < 2; ++c) {
            short8 av[MI], bv[NI];
            #pragma unroll
            for (int mi = 0; mi < MI; ++mi)
                av[mi] = *(const short8*)&smemA[c * (TM * 32) + (wm * MI * 16 + mi * 16 + lr) * 32 + quad * 8];
            #pragma unroll
            for (int ni = 0; ni < NI; ++ni)
                bv[ni] = *(const short8*)&smemB[c * 4096 + (wn * NI * 16 + ni * 16 + lr) * 32 + quad * 8];
            #pragma unroll
            for (int mi = 0; mi < MI; ++mi)
                #pragma unroll
                for (int ni = 0; ni < NI; ++ni)
                    acc[mi][ni] = __builtin_amdgcn_mfma_f32_16x16x32_bf16(
                        av[mi], bv[ni], acc[mi][ni], 0, 0, 0);
        }
        __syncthreads();
    }

    #pragma unroll
    for (int mi = 0; mi < MI; ++mi) {
        #pragma unroll
        for (int ni = 0; ni < NI; ++ni) {
            #pragma unroll
            for (int r = 0; r < 4; ++r) {
                const int row = bm + wm * MI * 16 + mi * 16 + quad * 4 + r;
                const int col = bn + wn * NI * 16 + ni * 16 + lr;
                if (PROJ) {
                    const float bb = (col < 256) ? bias[col]
                                   : (col < 512) ? bias2[col - 256]
                                                 : bias3[col - 512];
                    const float v = acc[mi][ni][r] + bb;
                    if (col < 256) Cb[(size_t)row * 256 + col] = f2bf(v);
                    else           Cb2[(size_t)row * 384 + (col - 256)] = f2bf(v);
                } else {
                    float v = acc[mi][ni][r] + bias[col];
                    if (RES) { if (row < M) v += R[(size_t)row * N + col]; }
                    if (RELU) v = fmaxf(v, 0.0f);
                    if (F32OUT) Cf[(size_t)row * N + col] = v;
                    if (BF16OUT) Cb[(size_t)row * N + col] = f2bf(v);
                }
            }
        }
    }
}

// ---------------------------------------------------------------------------
// Fused GEMM(N=256) + bias + residual + LayerNorm. Tile 32 rows x 256 cols;
// wave w owns cols [w*64,+64) (MI=2, NI=4). Grid = M_PAD/32 = 832 blocks.
// ---------------------------------------------------------------------------
template<bool HASB>
__global__ __launch_bounds__(256)
void mgemm_ln(const unsigned short* __restrict__ A,
              const unsigned short* __restrict__ BT,
              const float* __restrict__ bias,
              const float* __restrict__ R,
              const float* __restrict__ g,
              const float* __restrict__ beta,
              float* __restrict__ outF,
              unsigned short* __restrict__ outB,
              int M, int K)
{
    __shared__ __align__(16) unsigned short smemA[2 * 32 * 32];    // 4 KB
    __shared__ __align__(16) unsigned short smemB[2 * 256 * 32];   // 32 KB
    const int lane = threadIdx.x & 63;
    const int w    = threadIdx.x >> 6;
    const int lr   = lane & 15, quad = lane >> 4;
    const int bm   = blockIdx.x * 32;
    const int srow = lane >> 2;
    const int selt = (lane & 3) << 3;
    const int cA = w >> 1, rh = w & 1;    // A-staging: wave -> (chunk, row half)

    floatx4 acc[2][4];
    #pragma unroll
    for (int i = 0; i < 2; ++i)
        #pragma unroll
        for (int j = 0; j < 4; ++j)
            acc[i][j] = (floatx4){0.f, 0.f, 0.f, 0.f};

    for (int k0 = 0; k0 < K; k0 += 64) {
        const unsigned short* ga = A + (size_t)(bm + rh * 16 + srow) * K + k0 + cA * 32 + selt;
        __builtin_amdgcn_global_load_lds(AS1C(ga), AS3(smemA + cA * 1024 + rh * 512), 16, 0, 0);
        #pragma unroll
        for (int c = 0; c < 2; ++c) {
            #pragma unroll
            for (int jj = 0; jj < 4; ++jj) {
                const int j = 4 * w + jj;
                const unsigned short* gb = BT + (size_t)(j * 16 + srow) * K + k0 + c * 32 + selt;
                __builtin_amdgcn_global_load_lds(AS1C(gb), AS3(smemB + c * 8192 + j * 512), 16, 0, 0);
            }
        }
        __syncthreads();
        #pragma unroll
        for (int c = 0; c < 2; ++c) {
            short8 av[2], bv[4];
            #pragma unroll
            for (int mi = 0; mi < 2; ++mi)
                av[mi] = *(const short8*)&smemA[c * 1024 + (mi * 16 + lr) * 32 + quad * 8];
            #pragma unroll
            for (int ni = 0; ni < 4; ++ni)
                bv[ni] = *(const short8*)&smemB[c * 8192 + (w * 64 + ni * 16 + lr) * 32 + quad * 8];
            #pragma unroll
            for (int mi = 0; mi < 2; ++mi)
                #pragma unroll
                for (int ni = 0; ni < 4; ++ni)
                    acc[mi][ni] = __builtin_amdgcn_mfma_f32_16x16x32_bf16(
                        av[mi], bv[ni], acc[mi][ni], 0, 0, 0);
        }
        __syncthreads();
    }

    float bs[4], gs[4], bts[4];
    #pragma unroll
    for (int ni = 0; ni < 4; ++ni) {
        const int col = w * 64 + ni * 16 + lr;
        bs[ni] = bias[col]; gs[ni] = g[col]; bts[ni] = beta[col];
    }
    float* lnbuf = (float*)smemA;   // 32 rows x 8 floats = 1 KB

    #pragma unroll
    for (int mi = 0; mi < 2; ++mi) {
        #pragma unroll
        for (int r = 0; r < 4; ++r) {
            const int rl = mi * 16 + quad * 4 + r;
            const int grow = bm + rl;
            const bool act = grow < M;
            float p = 0.f, q = 0.f;
            #pragma unroll
            for (int ni = 0; ni < 4; ++ni) {
                const int col = w * 64 + ni * 16 + lr;
                const float rv = act ? R[(size_t)grow * 256 + col] : 0.f;
                const float x = acc[mi][ni][r] + bs[ni] + rv;
                acc[mi][ni][r] = x;
                p += x; q += x * x;
            }
            #pragma unroll
            for (int o = 1; o < 16; o <<= 1) {
                p += __shfl_xor(p, o, 64);
                q += __shfl_xor(q, o, 64);
            }
            if (lr == 0) {
                lnbuf[rl * 8 + 2 * w]     = p;
                lnbuf[rl * 8 + 2 * w + 1] = q;
            }
        }
    }
    __syncthreads();
    #pragma unroll
    for (int mi = 0; mi < 2; ++mi) {
        #pragma unroll
        for (int r = 0; r < 4; ++r) {
            const int rl = mi * 16 + quad * 4 + r;
            const int grow = bm + rl;
            const float4 pa = *(const float4*)&lnbuf[rl * 8];
            const float4 pb = *(const float4*)&lnbuf[rl * 8 + 4];
            const float s  = pa.x + pa.z + pb.x + pb.z;
            const float s2 = pa.y + pa.w + pb.y + pb.w;
            const float mean = s * (1.0f / 256.0f);
            const float var  = s2 * (1.0f / 256.0f) - mean * mean;
            const float rs   = rsqrtf(var + 1e-5f);
            if (grow < M) {
                #pragma unroll
                for (int ni = 0; ni < 4; ++ni) {
                    const int col = w * 64 + ni * 16 + lr;
                    const float y = (acc[mi][ni][r] - mean) * rs * gs[ni] + bts[ni];
                    outF[(size_t)grow * 256 + col] = y;
                    if (HASB) outB[(size_t)grow * 256 + col] = f2bf(y);
                }
            }
        }
    }
}

// ---------------------------------------------------------------------------
// fp32 [M,256] -> bf16 [M_PAD,256] with zero padding rows (layer 0 only)
// ---------------------------------------------------------------------------
__global__ __launch_bounds__(256)
void convpad(const float* __restrict__ X, unsigned short* __restrict__ Y, int M)
{
    const int idx = blockIdx.x * 256 + threadIdx.x;
    const int row = idx >> 6;
    const int c4  = (idx & 63) << 2;
    if (row >= M_PAD) return;
    float4 v = {0.f, 0.f, 0.f, 0.f};
    if (row < M) v = ((const float4*)(X + (size_t)row * 256))[c4 >> 2];
    unsigned p0 = (unsigned)f2bf(v.x) | ((unsigned)f2bf(v.y) << 16);
    unsigned p1 = (unsigned)f2bf(v.z) | ((unsigned)f2bf(v.w) << 16);
    uint2 o; o.x = p0; o.y = p1;
    *(uint2*)(Y + (size_t)row * 256 + c4) = o;
}

// ---------------------------------------------------------------------------
// Merged weight transpose+convert (12 segments, one dispatch).
// ---------------------------------------------------------------------------
struct WJobs {
    const float* W[12];
    unsigned short* WT[12];
    int K[12], N[12], tx[12], start[12];
};

__global__ __launch_bounds__(256)
void wtrans_all(WJobs jb)
{
    __shared__ float t[32][33];
    const int bx = blockIdx.x;
    int seg = 0;
    #pragma unroll
    for (int s = 1; s < 12; ++s) if (bx >= jb.start[s]) seg = s;
    const float* W = jb.W[seg];
    unsigned short* WT = jb.WT[seg];
    const int K = jb.K[seg], N = jb.N[seg], tx = jb.tx[seg];
    const int local = bx - jb.start[seg];
    const int n0 = (local % tx) * 32, k0 = (local / tx) * 32;
    const int c = threadIdx.x & 31, r0 = threadIdx.x >> 5;
    #pragma unroll
    for (int rr = r0; rr < 32; rr += 8)
        t[rr][c] = W[(size_t)(k0 + rr) * N + n0 + c];
    __syncthreads();
    #pragma unroll
    for (int rr = r0; rr < 32; rr += 8)
        WT[(size_t)(n0 + rr) * K + k0 + c] = f2bf(t[c][rr]);
}

// ---------------------------------------------------------------------------
// MSDA, 2-phase. Phase A: bf16 off/attn reads, division-free coordinates
// (x = ref*W - 0.5 + off), __expf softmax. Phase B: packed float2 fma.
// ---------------------------------------------------------------------------
__global__ __launch_bounds__(256)
void msda_kernel(const unsigned short* __restrict__ valb,
                 const unsigned short* __restrict__ oab,   // [M,384] bf16
                 const float* __restrict__ vr,
                 unsigned short* __restrict__ out)
{
    __shared__ __align__(16) char smeta[8 * 128 * 32];
    const int t = threadIdx.x;

    {
        const int wv = t >> 6, lane = t & 63;
        const int lqA = wv * 2 + (lane >> 5);
        const int bq = blockIdx.x * 8 + lqA;
        const int h = (lane >> 2) & 7;
        const int j = lane & 3;
        if (bq < M_TOT) {
            const int b = (bq >= S_TOT) ? 1 : 0;
            const int q = bq - b * S_TOT;
            const int bofs = b * (S_TOT * 512);
            int Hq, rr, cc, lq;
            if (q < 10000)      { lq = 0; Hq = 100; rr = q / 100;              cc = q - rr * 100; }
            else if (q < 12500) { lq = 1; Hq = 50;  int r2 = q - 10000; rr = r2 / 50; cc = r2 - rr * 50; }
            else if (q < 13125) { lq = 2; Hq = 25;  int r2 = q - 12500; rr = r2 / 25; cc = r2 - rr * 25; }
            else                { lq = 3; Hq = 13;  int r2 = q - 13125; rr = r2 / 13; cc = r2 - rr * 13; }
            const float rxb = (cc + 0.5f) / (vr[(b * 4 + lq) * 2 + 0] * (float)Hq);
            const float ryb = (rr + 0.5f) / (vr[(b * 4 + lq) * 2 + 1] * (float)Hq);
            const int HWt[4] = {100, 50, 25, 13};
            const int stt[4] = {0, 10000, 12500, 13125};
            const int HW = HWt[j], st = stt[j];
            const float fW = (float)HW;
            // (ref + off/W)*W - 0.5 == ref*W - 0.5 + off  (1-ulp-level identity)
            const float refxw = rxb * vr[(b * 4 + j) * 2 + 0] * fW - 0.5f;
            const float refyw = ryb * vr[(b * 4 + j) * 2 + 1] * fW - 0.5f;
            const unsigned short* row = oab + (size_t)bq * 384;
            const uint2 lgu = *(const uint2*)(row + 256 + h * 16 + j * 4);
            const float l0 = bflo(lgu.x), l1 = bfhi(lgu.x);
            const float l2 = bflo(lgu.y), l3 = bfhi(lgu.y);
            float mx = fmaxf(fmaxf(l0, l1), fmaxf(l2, l3));
            mx = fmaxf(mx, __shfl_xor(mx, 1, 64));
            mx = fmaxf(mx, __shfl_xor(mx, 2, 64));
            const float e0 = __expf(l0 - mx), e1 = __expf(l1 - mx);
            const float e2 = __expf(l2 - mx), e3 = __expf(l3 - mx);
            float ss = e0 + e1 + e2 + e3;
            ss += __shfl_xor(ss, 1, 64);
            ss += __shfl_xor(ss, 2, 64);
            const float inv = 1.0f / ss;
            const uint4 ou = *(const uint4*)(row + h * 32 + j * 8);
            const float oxs[4] = {bflo(ou.x), bflo(ou.y), bflo(ou.z), bflo(ou.w)};
            const float oys[4] = {bfhi(ou.x), bfhi(ou.y), bfhi(ou.z), bfhi(ou.w)};
            const float aw[4]  = {e0 * inv, e1 * inv, e2 * inv, e3 * inv};
            char* mb = smeta + (size_t)(lqA * 128 + h * 16 + j * 4) * 32;
            const int swz = ((h * 4 + j) & 7) << 4;
            #pragma unroll
            for (int p = 0; p < 4; ++p) {
                const float x = refxw + oxs[p];
                const float y = refyw + oys[p];
                const float x0f = floorf(x), y0f = floorf(y);
                const int x0 = (int)x0f, y0 = (int)y0f;
                const float fx = x - x0f, fy = y - y0f;
                const float wb[4] = {(1.f - fx) * (1.f - fy), fx * (1.f - fy),
                                     (1.f - fx) * fy,         fx * fy};
                const int xs[2] = {x0, x0 + 1};
                const int ys2[2] = {y0, y0 + 1};
                int iv[4]; float wv4[4];
                #pragma unroll
                for (int k = 0; k < 4; ++k) {
                    const int xi = xs[k & 1], yi = ys2[k >> 1];
                    const bool vld = ((unsigned)xi < (unsigned)HW) && ((unsigned)yi < (unsigned)HW);
                    const int xc = min(max(xi, 0), HW - 1);
                    const int yc = min(max(yi, 0), HW - 1);
                    iv[k] = bofs + ((st + yc * HW + xc) << 9) + (h << 6);
                    wv4[k] = vld ? wb[k] * aw[p] : 0.0f;
                }
                int4 i4; i4.x = iv[0]; i4.y = iv[1]; i4.z = iv[2]; i4.w = iv[3];
                float4 w4; w4.x = wv4[0]; w4.y = wv4[1]; w4.z = wv4[2]; w4.w = wv4[3];
                *(int4*)(mb + ((p * 32) ^ swz)) = i4;
                *(float4*)(mb + ((p * 32 + 16) ^ swz)) = w4;
            }
        }
    }
    __syncthreads();
    {
        const int lq2 = t >> 5;
        const int r = t & 31;
        const int h2 = r >> 2;
        const int cg = r & 3;
        const int bq2 = blockIdx.x * 8 + lq2;
        if (bq2 < M_TOT) {
            const char* vbase = (const char*)valb;
            const unsigned cgo = cg * 16;
            floatx2 a0 = {0.f, 0.f}, a1 = {0.f, 0.f}, a2 = {0.f, 0.f}, a3 = {0.f, 0.f};
            const char* mb2 = smeta + (size_t)(lq2 * 128 + h2 * 16) * 32;
            #pragma unroll 4
            for (int s = 0; s < 16; ++s) {
                const int swz2 = ((h2 * 4 + (s >> 2)) & 7) << 4;
                const int4  iv = *(const int4*)(mb2 + ((s * 32) ^ swz2));
                const float4 w4 = *(const float4*)(mb2 + ((s * 32 + 16) ^ swz2));
                const uint4 u0 = *(const uint4*)(vbase + (unsigned)(iv.x + cgo));
                const uint4 u1 = *(const uint4*)(vbase + (unsigned)(iv.y + cgo));
                const uint4 u2 = *(const uint4*)(vbase + (unsigned)(iv.z + cgo));
                const uint4 u3 = *(const uint4*)(vbase + (unsigned)(iv.w + cgo));
                #define ACC8(UU, WW) { \
                    const floatx2 w2 = {WW, WW}; \
                    const floatx2 t0 = {bflo(UU.x), bfhi(UU.x)}; \
                    const floatx2 t1 = {bflo(UU.y), bfhi(UU.y)}; \
                    const floatx2 t2 = {bflo(UU.z), bfhi(UU.z)}; \
                    const floatx2 t3 = {bflo(UU.w), bfhi(UU.w)}; \
                    a0 += w2 * t0; a1 += w2 * t1; a2 += w2 * t2; a3 += w2 * t3; }
                ACC8(u0, w4.x) ACC8(u1, w4.y) ACC8(u2, w4.z) ACC8(u3, w4.w)
                #undef ACC8
            }
            uint4 o;
            o.x = (unsigned)f2bf(a0.x) | ((unsigned)f2bf(a0.y) << 16);
            o.y = (unsigned)f2bf(a1.x) | ((unsigned)f2bf(a1.y) << 16);
            o.z = (unsigned)f2bf(a2.x) | ((unsigned)f2bf(a2.y) << 16);
            o.w = (unsigned)f2bf(a3.x) | ((unsigned)f2bf(a3.y) << 16);
            *(uint4*)(out + (size_t)bq2 * 256 + h2 * 32 + cg * 8) = o;
        }
    }
}

// ---------------------------------------------------------------------------
// Host-side orchestration
// ---------------------------------------------------------------------------
extern "C" void kernel_launch(void* const* d_in, const int* in_sizes, int n_in,
                              void* d_out, int out_size, void* d_ws, size_t ws_size,
                              hipStream_t stream)
{
    const float* src    = (const float*)d_in[0];
    const float* vr     = (const float*)d_in[2];
    const float* W_off  = (const float*)d_in[3];
    const float* b_off  = (const float*)d_in[4];
    const float* W_attn = (const float*)d_in[5];
    const float* b_attn = (const float*)d_in[6];
    const float* W_val  = (const float*)d_in[7];
    const float* b_val  = (const float*)d_in[8];
    const float* W_out  = (const float*)d_in[9];
    const float* b_out  = (const float*)d_in[10];
    const float* ln1_g  = (const float*)d_in[11];
    const float* ln1_b  = (const float*)d_in[12];
    const float* W1     = (const float*)d_in[13];
    const float* b1     = (const float*)d_in[14];
    const float* W2     = (const float*)d_in[15];
    const float* b2     = (const float*)d_in[16];
    const float* ln2_g  = (const float*)d_in[17];
    const float* ln2_b  = (const float*)d_in[18];
    float* out = (float*)d_out;

    const int M = M_TOT;

    // --- workspace (bytes), total 112,066,560 ---
    // [0,          54,525,952)  HBF bf16 [M_PAD,1024]; overlays:
    //     OAB  bf16 [M_PAD,384] at [0, 20,447,232)
    //     VALB bf16 [M_PAD,256] at [20,447,232, 34,078,720)
    // [54,525,952, 81,788,928)  T1  f32 [M_PAD,256]
    // [81,788,928, 95,420,416)  RB  bf16 [M_PAD,256]
    // [95,420,416,109,051,904)  YBF bf16 [M_PAD,256]
    // [109,051,904,112,066,560) WT  transposed weights
    char* wsb = (char*)d_ws;
    unsigned short* HBF  = (unsigned short*)wsb;
    unsigned short* OAB  = (unsigned short*)wsb;
    unsigned short* VALB = (unsigned short*)(wsb + 20447232);
    float*          T1   = (float*)(wsb + 54525952);
    unsigned short* RB   = (unsigned short*)(wsb + 81788928);
    unsigned short* YBF  = (unsigned short*)(wsb + 95420416);
    unsigned short* WT   = (unsigned short*)(wsb + 109051904);

    const size_t LWT = 753664;
    const size_t oProj = 0, oOut = 163840, oW1 = 229376, oW2 = 491520;

    WJobs jb;
    int startAcc = 0;
    for (int i = 0; i < 2; ++i) {
        unsigned short* wt = WT + i * LWT;
        const float* srcs[6] = {W_val + i * 65536, W_off + i * 65536, W_attn + i * 32768,
                                W_out + i * 65536, W1 + i * 262144, W2 + i * 262144};
        unsigned short* dsts[6] = {wt + oProj, wt + oProj + 65536, wt + oProj + 131072,
                                   wt + oOut, wt + oW1, wt + oW2};
        const int Ks[6] = {256, 256, 256, 256, 256, 1024};
        const int Ns[6] = {256, 256, 128, 256, 1024, 256};
        for (int s = 0; s < 6; ++s) {
            const int idx = i * 6 + s;
            jb.W[idx] = srcs[s]; jb.WT[idx] = dsts[s];
            jb.K[idx] = Ks[s]; jb.N[idx] = Ns[s]; jb.tx[idx] = Ns[s] / 32;
            jb.start[idx] = startAcc;
            startAcc += (Ns[s] / 32) * (Ks[s] / 32);
        }
    }
    wtrans_all<<<dim3(startAcc), 256, 0, stream>>>(jb);

    const int GM128 = M_PAD / 128;  // 208
    const int GM64  = M_PAD / 64;   // 416
    const int GL32  = M_PAD / 32;   // 832
    const dim3 blk(256);

    for (int i = 0; i < 2; ++i) {
        const float* xin = (i == 0) ? src : out;
        unsigned short* wt = WT + i * LWT;

        if (i == 0)
            convpad<<<dim3(M_PAD / 4), blk, 0, stream>>>(src, RB, M);

        // merged projections: N=640 -> VALB (bf16) + OAB (bf16)
        mgemm<64, false, false, false, false, true><<<dim3(5, GM64), blk, 0, stream>>>(
            RB, wt + oProj, b_val + i * 256, b_off + i * 256, b_attn + i * 128,
            nullptr, nullptr, VALB, OAB, M, 640, 256);

        // deformable sampling
        msda_kernel<<<dim3((M + 7) / 8), blk, 0, stream>>>(VALB, OAB, vr, YBF);

        // fused out-proj + residual(xin) + LN1 -> T1 (f32) + RB (bf16)
        mgemm_ln<true><<<dim3(GL32), blk, 0, stream>>>(
            YBF, wt + oOut, b_out + i * 256, xin,
            ln1_g + i * 256, ln1_b + i * 256, T1, RB, M, 256);

        // FFN1 (relu, bf16 hidden overlays OAB+VALB region)
        mgemm<128, true, false, false, true, false><<<dim3(8, GM128), blk, 0, stream>>>(
            RB, wt + oW1, b1 + i * 1024, nullptr, nullptr,
            nullptr, nullptr, HBF, nullptr, M, 1024, 256);

        // fused FFN2 + residual(T1) + LN2 -> out (f32) [+ RB bf16 on layer 0]
        if (i == 0)
            mgemm_ln<true><<<dim3(GL32), blk, 0, stream>>>(
                HBF, wt + oW2, b2 + i * 256, T1,
                ln2_g + i * 256, ln2_b + i * 256, out, RB, M, 1024);
        else
            mgemm_ln<false><<<dim3(GL32), blk, 0, stream>>>(
                HBF, wt + oW2, b2 + i * 256, T1,
                ln2_g + i * 256, ln2_b + i * 256, out, nullptr, M, 1024);
    }
}